// Round 1
// baseline (748.134 us; speedup 1.0000x reference)
//
#include <hip/hip_runtime.h>
#include <stdint.h>

#define BDIM 4
#define TDIM 4096
#define CDIM 1024
#define MDIM (BDIM * TDIM) // 16384

typedef __attribute__((ext_vector_type(8))) short bf16x8;
typedef __attribute__((ext_vector_type(4))) float f32x4;

__device__ __forceinline__ unsigned short f2bf(float f) {
    unsigned u = __builtin_bit_cast(unsigned, f);
    u = u + 0x7fffu + ((u >> 16) & 1u); // RNE
    return (unsigned short)(u >> 16);
}
__device__ __forceinline__ float bf2f(unsigned short h) {
    unsigned u = ((unsigned)h) << 16;
    return __builtin_bit_cast(float, u);
}

typedef __attribute__((address_space(1))) const unsigned int g_u32;
typedef __attribute__((address_space(3))) unsigned int l_u32;
__device__ __forceinline__ void gload_lds16(const void* g, void* l) {
    __builtin_amdgcn_global_load_lds((g_u32*)g, (l_u32*)l, 16, 0, 0);
}

// ---------------- fp32 -> bf16 cast (vectorized) ----------------
__global__ void castk(const float* __restrict__ src, unsigned short* __restrict__ dst, int n4) {
    int i = blockIdx.x * blockDim.x + threadIdx.x;
    int stride = gridDim.x * blockDim.x;
    for (int j = i; j < n4; j += stride) {
        float4 f = ((const float4*)src)[j];
        ushort4 o;
        o.x = f2bf(f.x); o.y = f2bf(f.y); o.z = f2bf(f.z); o.w = f2bf(f.w);
        ((ushort4*)dst)[j] = o;
    }
}

// ---------------- bf16 GEMM:  Y[m,n] = sum_k A[m,k] * Bw[n,k] ----------------
// 128x128 tile, 4 waves (2x2), BK=32, global_load_lds width16, 16x16x32 MFMA.
// MODE 0: store fp32.  MODE 1: sigmoid -> bf16 store.
template <int MODE>
__global__ __launch_bounds__(256, 2) void gemm_bt(
    const unsigned short* __restrict__ A,   // [M,K] bf16
    const unsigned short* __restrict__ Bw,  // [N,K] bf16
    void* __restrict__ Y, int K, int N)
{
    __shared__ unsigned short Ash[128 * 32];
    __shared__ unsigned short Bsh[128 * 32];

    const int tid  = threadIdx.x;
    const int wave = tid >> 6;
    const int lane = tid & 63;
    const int row0 = blockIdx.x * 128;
    const int col0 = blockIdx.y * 128;

    const int wm = wave >> 1, wn = wave & 1;          // 2x2 wave grid, 64x64 per wave
    const int lrow = lane & 15;
    const int lkB  = ((lane >> 4) * 8) * 2;           // byte offset of k-slice within a 64B row

    f32x4 acc[4][4] = {};

    for (int k0 = 0; k0 < K; k0 += 32) {
        // stage A,B tiles: 512 chunks of 16B each per tile
#pragma unroll
        for (int j = 0; j < 2; ++j) {
            int chunk = (j * 4 + wave) * 64 + lane;   // 0..511, lane-linear per wave
            int r  = chunk >> 2;                      // row 0..127
            int c8 = (chunk & 3) * 8;                 // col 0,8,16,24
            const unsigned short* ga = A  + (size_t)(row0 + r) * K + k0 + c8;
            const unsigned short* gb = Bw + (size_t)(col0 + r) * K + k0 + c8;
            gload_lds16(ga, (char*)Ash + chunk * 16);
            gload_lds16(gb, (char*)Bsh + chunk * 16);
        }
        __syncthreads();

        bf16x8 af[4], bfr[4];
#pragma unroll
        for (int mi = 0; mi < 4; ++mi)
            af[mi] = *(const bf16x8*)((const char*)Ash + (wm * 64 + mi * 16 + lrow) * 64 + lkB);
#pragma unroll
        for (int ni = 0; ni < 4; ++ni)
            bfr[ni] = *(const bf16x8*)((const char*)Bsh + (wn * 64 + ni * 16 + lrow) * 64 + lkB);
#pragma unroll
        for (int mi = 0; mi < 4; ++mi)
#pragma unroll
            for (int ni = 0; ni < 4; ++ni)
                acc[mi][ni] = __builtin_amdgcn_mfma_f32_16x16x32_bf16(af[mi], bfr[ni], acc[mi][ni], 0, 0, 0);
        __syncthreads();
    }

    // epilogue: C/D layout col=lane&15, row=(lane>>4)*4+j  (m89-verified)
    const int crow = (lane >> 4) * 4;
    const int ccol = lane & 15;
#pragma unroll
    for (int mi = 0; mi < 4; ++mi)
#pragma unroll
        for (int ni = 0; ni < 4; ++ni) {
            int gr0 = row0 + wm * 64 + mi * 16 + crow;
            int gc  = col0 + wn * 64 + ni * 16 + ccol;
#pragma unroll
            for (int j = 0; j < 4; ++j) {
                float val = acc[mi][ni][j];
                size_t off = (size_t)(gr0 + j) * N + gc;
                if (MODE == 0) {
                    ((float*)Y)[off] = val;
                } else {
                    float s = 1.0f / (1.0f + __expf(-val));
                    ((unsigned short*)Y)[off] = f2bf(s);
                }
            }
        }
}

// ---------------- WKV sequential scan (fused r*wkv, bf16 out) ----------------
#define CH 16
__global__ __launch_bounds__(256) void rwkv_scan(
    const float* __restrict__ kf, const float* __restrict__ vf,
    const unsigned short* __restrict__ rb,
    const float* __restrict__ td, const float* __restrict__ tf,
    const float* __restrict__ aa0, const float* __restrict__ bb0, const float* __restrict__ pp0,
    unsigned short* __restrict__ rwkvb, float* __restrict__ stout /* d_out + B*T*C */)
{
    const int tid = blockIdx.x * 256 + threadIdx.x;   // 0 .. B*C-1
    const int c = tid & (CDIM - 1);
    const int b = tid >> 10;

    const float w = __expf(td[c]);
    const float u = tf[c];
    float aa = aa0[tid], bb = bb0[tid], pp = pp0[tid];

    const size_t base = (size_t)b * TDIM * CDIM + c;

    float kA[CH], vA[CH], rA[CH];
    float kB[CH], vB[CH], rB[CH];

    // prefetch chunk 0
#pragma unroll
    for (int i = 0; i < CH; ++i) {
        size_t idx = base + (size_t)i * CDIM;
        kA[i] = kf[idx];
        vA[i] = vf[idx];
        rA[i] = bf2f(rb[idx]);
    }

    const int nch = TDIM / CH;
    for (int ch = 0; ch < nch; ++ch) {
        // issue next chunk's loads before compute (latency hiding)
        if (ch + 1 < nch) {
#pragma unroll
            for (int i = 0; i < CH; ++i) {
                size_t idx = base + (size_t)((ch + 1) * CH + i) * CDIM;
                kB[i] = kf[idx];
                vB[i] = vf[idx];
                rB[i] = bf2f(rb[idx]);
            }
        }
        // compute current chunk
#pragma unroll
        for (int i = 0; i < CH; ++i) {
            float kt = kA[i], vt = vA[i], rt = rA[i];
            // output (uses state BEFORE update)
            float ww = u + kt;
            float p  = fmaxf(pp, ww);
            float e1 = __expf(pp - p);
            float e2 = __expf(ww - p);
            float wkv = (e1 * aa + e2 * vt) / (e1 * bb + e2);
            size_t idx = base + (size_t)(ch * CH + i) * CDIM;
            rwkvb[idx] = f2bf(rt * wkv);
            // state update
            float ww2 = pp - w;
            float p2  = fmaxf(ww2, kt);
            float e1b = __expf(ww2 - p2);
            float e2b = __expf(kt - p2);
            aa = e1b * aa + e2b * vt;
            bb = e1b * bb + e2b;
            pp = p2;
        }
        // rotate buffers
#pragma unroll
        for (int i = 0; i < CH; ++i) { kA[i] = kB[i]; vA[i] = vB[i]; rA[i] = rB[i]; }
    }

    // final states -> d_out tail (order: aa, bb, pp)
    stout[tid] = aa;
    stout[BDIM * CDIM + tid] = bb;
    stout[2 * BDIM * CDIM + tid] = pp;
}

extern "C" void kernel_launch(void* const* d_in, const int* in_sizes, int n_in,
                              void* d_out, int out_size, void* d_ws, size_t ws_size,
                              hipStream_t stream) {
    const float* x   = (const float*)d_in[0];
    const float* kw  = (const float*)d_in[1];
    const float* vw  = (const float*)d_in[2];
    const float* rw  = (const float*)d_in[3];
    const float* ow  = (const float*)d_in[4];
    const float* td  = (const float*)d_in[5];
    const float* tf  = (const float*)d_in[6];
    const float* aa0 = (const float*)d_in[7];
    const float* bb0 = (const float*)d_in[8];
    const float* pp0 = (const float*)d_in[9];
    float* out = (float*)d_out;

    char* ws = (char*)d_ws;
    unsigned short* xb    = (unsigned short*)(ws);               // 33,554,432 B
    unsigned short* kwb   = (unsigned short*)(ws + 33554432);    //  2,097,152 B
    unsigned short* vwb   = (unsigned short*)(ws + 35651584);
    unsigned short* rwb   = (unsigned short*)(ws + 37748736);
    unsigned short* owb   = (unsigned short*)(ws + 39845888);
    float*          kfb   = (float*)(ws + 41943040);             // 67,108,864 B
    float*          vfb   = (float*)(ws + 109051904);            // 67,108,864 B
    unsigned short* rbb   = (unsigned short*)(ws + 176160768);   // 33,554,432 B
    unsigned short* rwkvb = (unsigned short*)(ws + 209715200);   // 33,554,432 B
    // total ws use: 243,269,632 B

    // casts to bf16
    castk<<<2048, 256, 0, stream>>>(x,  xb,  MDIM * CDIM / 4);
    castk<<<512,  256, 0, stream>>>(kw, kwb, CDIM * CDIM / 4);
    castk<<<512,  256, 0, stream>>>(vw, vwb, CDIM * CDIM / 4);
    castk<<<512,  256, 0, stream>>>(rw, rwb, CDIM * CDIM / 4);
    castk<<<512,  256, 0, stream>>>(ow, owb, CDIM * CDIM / 4);

    dim3 gg(MDIM / 128, CDIM / 128);
    gemm_bt<0><<<gg, 256, 0, stream>>>(xb, kwb, kfb, CDIM, CDIM);
    gemm_bt<0><<<gg, 256, 0, stream>>>(xb, vwb, vfb, CDIM, CDIM);
    gemm_bt<1><<<gg, 256, 0, stream>>>(xb, rwb, rbb, CDIM, CDIM);

    rwkv_scan<<<16, 256, 0, stream>>>(kfb, vfb, rbb, td, tf, aa0, bb0, pp0,
                                      rwkvb, out + (size_t)MDIM * CDIM);

    gemm_bt<0><<<gg, 256, 0, stream>>>(rwkvb, owb, out, CDIM, CDIM);
}

// Round 2
// 267.100 us; speedup vs baseline: 2.8010x; 2.8010x over previous
//
#include <hip/hip_runtime.h>
#include <stdint.h>

#define BDIM 4
#define TDIM 4096
#define CDIM 1024
#define MDIM (BDIM * TDIM) // 16384
#define SSEG 64            // segments along T
#define LSEG 64            // steps per segment (TDIM/SSEG)
#define NCH  (BDIM * CDIM) // 4096 channels

typedef __attribute__((ext_vector_type(8))) short bf16x8;
typedef __attribute__((ext_vector_type(4))) float f32x4;

__device__ __forceinline__ unsigned short f2bf(float f) {
    unsigned u = __builtin_bit_cast(unsigned, f);
    u = u + 0x7fffu + ((u >> 16) & 1u); // RNE
    return (unsigned short)(u >> 16);
}
__device__ __forceinline__ float bf2f(unsigned short h) {
    unsigned u = ((unsigned)h) << 16;
    return __builtin_bit_cast(float, u);
}

typedef __attribute__((address_space(1))) const unsigned int g_u32;
typedef __attribute__((address_space(3))) unsigned int l_u32;
__device__ __forceinline__ void gload_lds16(const void* g, void* l) {
    __builtin_amdgcn_global_load_lds((g_u32*)g, (l_u32*)l, 16, 0, 0);
}

// ---------------- fp32 -> bf16 cast (vectorized) ----------------
__global__ void castk(const float* __restrict__ src, unsigned short* __restrict__ dst, int n4) {
    int i = blockIdx.x * blockDim.x + threadIdx.x;
    int stride = gridDim.x * blockDim.x;
    for (int j = i; j < n4; j += stride) {
        float4 f = ((const float4*)src)[j];
        ushort4 o;
        o.x = f2bf(f.x); o.y = f2bf(f.y); o.z = f2bf(f.z); o.w = f2bf(f.w);
        ((ushort4*)dst)[j] = o;
    }
}

// ---------------- bf16 GEMM:  Y[m,n] = sum_k A[m,k] * Bw[n,k] ----------------
// 128x128 tile, 4 waves (2x2), BK=32, global_load_lds width16, 16x16x32 MFMA.
// MODE 0: store fp32.  MODE 1: sigmoid -> bf16 store.
template <int MODE>
__global__ __launch_bounds__(256, 2) void gemm_bt(
    const unsigned short* __restrict__ A,   // [M,K] bf16
    const unsigned short* __restrict__ Bw,  // [N,K] bf16
    void* __restrict__ Y, int K, int N)
{
    __shared__ unsigned short Ash[128 * 32];
    __shared__ unsigned short Bsh[128 * 32];

    const int tid  = threadIdx.x;
    const int wave = tid >> 6;
    const int lane = tid & 63;
    const int row0 = blockIdx.x * 128;
    const int col0 = blockIdx.y * 128;

    const int wm = wave >> 1, wn = wave & 1;          // 2x2 wave grid, 64x64 per wave
    const int lrow = lane & 15;
    const int lkB  = ((lane >> 4) * 8) * 2;           // byte offset of k-slice within a 64B row

    f32x4 acc[4][4] = {};

    for (int k0 = 0; k0 < K; k0 += 32) {
        // stage A,B tiles: 512 chunks of 16B each per tile
#pragma unroll
        for (int j = 0; j < 2; ++j) {
            int chunk = (j * 4 + wave) * 64 + lane;   // 0..511, lane-linear per wave
            int r  = chunk >> 2;                      // row 0..127
            int c8 = (chunk & 3) * 8;                 // col 0,8,16,24
            const unsigned short* ga = A  + (size_t)(row0 + r) * K + k0 + c8;
            const unsigned short* gb = Bw + (size_t)(col0 + r) * K + k0 + c8;
            gload_lds16(ga, (char*)Ash + chunk * 16);
            gload_lds16(gb, (char*)Bsh + chunk * 16);
        }
        __syncthreads();

        bf16x8 af[4], bfr[4];
#pragma unroll
        for (int mi = 0; mi < 4; ++mi)
            af[mi] = *(const bf16x8*)((const char*)Ash + (wm * 64 + mi * 16 + lrow) * 64 + lkB);
#pragma unroll
        for (int ni = 0; ni < 4; ++ni)
            bfr[ni] = *(const bf16x8*)((const char*)Bsh + (wn * 64 + ni * 16 + lrow) * 64 + lkB);
#pragma unroll
        for (int mi = 0; mi < 4; ++mi)
#pragma unroll
            for (int ni = 0; ni < 4; ++ni)
                acc[mi][ni] = __builtin_amdgcn_mfma_f32_16x16x32_bf16(af[mi], bfr[ni], acc[mi][ni], 0, 0, 0);
        __syncthreads();
    }

    // epilogue: C/D layout col=lane&15, row=(lane>>4)*4+j  (m89-verified)
    const int crow = (lane >> 4) * 4;
    const int ccol = lane & 15;
#pragma unroll
    for (int mi = 0; mi < 4; ++mi)
#pragma unroll
        for (int ni = 0; ni < 4; ++ni) {
            int gr0 = row0 + wm * 64 + mi * 16 + crow;
            int gc  = col0 + wn * 64 + ni * 16 + ccol;
#pragma unroll
            for (int j = 0; j < 4; ++j) {
                float val = acc[mi][ni][j];
                size_t off = (size_t)(gr0 + j) * N + gc;
                if (MODE == 0) {
                    ((float*)Y)[off] = val;
                } else {
                    float s = 1.0f / (1.0f + __expf(-val));
                    ((unsigned short*)Y)[off] = f2bf(s);
                }
            }
        }
}

// ---------------- WKV segmented scan ----------------
// Phase 1: each wave-lane owns (channel q, segment s); local scan with zero init.
// mapping: lane = channel-in-group (coalesced), wave_global = cg + 64*s
__global__ __launch_bounds__(256) void wkv_phase1(
    const float* __restrict__ kf, const float* __restrict__ vf,
    const float* __restrict__ td,
    float* __restrict__ segA, float* __restrict__ segB, float* __restrict__ segP)
{
    const int tid  = blockIdx.x * 256 + threadIdx.x;   // 0 .. NCH*SSEG-1
    const int lane = tid & 63;
    const int wg   = tid >> 6;        // global wave id
    const int cg   = wg & 63;         // channel group
    const int s    = wg >> 6;         // segment
    const int q    = cg * 64 + lane;  // channel id 0..4095
    const int b    = q >> 10;
    const int c    = q & (CDIM - 1);

    const float w = __expf(td[c]);

    float aa = 0.0f, bb = 0.0f, pp = -1e38f;
    size_t idx = (size_t)b * TDIM * CDIM + (size_t)(s * LSEG) * CDIM + c;
#pragma unroll 4
    for (int i = 0; i < LSEG; ++i, idx += CDIM) {
        float kt = kf[idx];
        float vt = vf[idx];
        float ww2 = pp - w;
        float p2  = fmaxf(ww2, kt);
        float e1  = __expf(ww2 - p2);
        float e2  = __expf(kt - p2);
        aa = e1 * aa + e2 * vt;
        bb = e1 * bb + e2;
        pp = p2;
    }
    segA[s * NCH + q] = aa;
    segB[s * NCH + q] = bb;
    segP[s * NCH + q] = pp;
}

// Phase 2: per-channel sequential combine across SSEG segments (tiny).
__global__ __launch_bounds__(256) void wkv_phase2(
    const float* __restrict__ segA, const float* __restrict__ segB, const float* __restrict__ segP,
    const float* __restrict__ td,
    const float* __restrict__ aa0, const float* __restrict__ bb0, const float* __restrict__ pp0,
    float* __restrict__ preA, float* __restrict__ preB, float* __restrict__ preP,
    float* __restrict__ stout)
{
    const int tid = blockIdx.x * 256 + threadIdx.x;   // 0 .. NCH-1
    const int c = tid & (CDIM - 1);
    const float w  = __expf(td[c]);
    const float Lw = (float)LSEG * w;

    float aa = aa0[tid], bb = bb0[tid], pp = pp0[tid];
    for (int s = 0; s < SSEG; ++s) {
        preA[s * NCH + tid] = aa;
        preB[s * NCH + tid] = bb;
        preP[s * NCH + tid] = pp;
        float al = segA[s * NCH + tid];
        float bl = segB[s * NCH + tid];
        float pl = segP[s * NCH + tid];
        float ppd = pp - Lw;
        float p  = fmaxf(ppd, pl);
        float e1 = __expf(ppd - p);
        float e2 = __expf(pl - p);
        aa = e1 * aa + e2 * al;
        bb = e1 * bb + e2 * bl;
        pp = p;
    }
    stout[tid]            = aa;
    stout[NCH + tid]      = bb;
    stout[2 * NCH + tid]  = pp;
}

// Phase 3: replay each segment from its exact prefix state, emit r*wkv (bf16).
__global__ __launch_bounds__(256) void wkv_phase3(
    const float* __restrict__ kf, const float* __restrict__ vf,
    const unsigned short* __restrict__ rb,
    const float* __restrict__ td, const float* __restrict__ tf,
    const float* __restrict__ preA, const float* __restrict__ preB, const float* __restrict__ preP,
    unsigned short* __restrict__ rwkvb)
{
    const int tid  = blockIdx.x * 256 + threadIdx.x;
    const int lane = tid & 63;
    const int wg   = tid >> 6;
    const int cg   = wg & 63;
    const int s    = wg >> 6;
    const int q    = cg * 64 + lane;
    const int b    = q >> 10;
    const int c    = q & (CDIM - 1);

    const float w = __expf(td[c]);
    const float u = tf[c];

    float aa = preA[s * NCH + q];
    float bb = preB[s * NCH + q];
    float pp = preP[s * NCH + q];

    size_t idx = (size_t)b * TDIM * CDIM + (size_t)(s * LSEG) * CDIM + c;
#pragma unroll 4
    for (int i = 0; i < LSEG; ++i, idx += CDIM) {
        float kt = kf[idx];
        float vt = vf[idx];
        float rt = bf2f(rb[idx]);
        // output (state BEFORE update)
        float ww = u + kt;
        float p  = fmaxf(pp, ww);
        float e1 = __expf(pp - p);
        float e2 = __expf(ww - p);
        float wkv = (e1 * aa + e2 * vt) / (e1 * bb + e2);
        rwkvb[idx] = f2bf(rt * wkv);
        // state update
        float ww2 = pp - w;
        float p2  = fmaxf(ww2, kt);
        float e1b = __expf(ww2 - p2);
        float e2b = __expf(kt - p2);
        aa = e1b * aa + e2b * vt;
        bb = e1b * bb + e2b;
        pp = p2;
    }
}

extern "C" void kernel_launch(void* const* d_in, const int* in_sizes, int n_in,
                              void* d_out, int out_size, void* d_ws, size_t ws_size,
                              hipStream_t stream) {
    const float* x   = (const float*)d_in[0];
    const float* kw  = (const float*)d_in[1];
    const float* vw  = (const float*)d_in[2];
    const float* rw  = (const float*)d_in[3];
    const float* ow  = (const float*)d_in[4];
    const float* td  = (const float*)d_in[5];
    const float* tf  = (const float*)d_in[6];
    const float* aa0 = (const float*)d_in[7];
    const float* bb0 = (const float*)d_in[8];
    const float* pp0 = (const float*)d_in[9];
    float* out = (float*)d_out;

    char* ws = (char*)d_ws;
    unsigned short* xb    = (unsigned short*)(ws);               // 33,554,432 B (dead after 3rd gemm)
    unsigned short* kwb   = (unsigned short*)(ws + 33554432);    //  2,097,152 B
    unsigned short* vwb   = (unsigned short*)(ws + 35651584);
    unsigned short* rwb   = (unsigned short*)(ws + 37748736);
    unsigned short* owb   = (unsigned short*)(ws + 39845888);
    float*          kfb   = (float*)(ws + 41943040);             // 67,108,864 B
    float*          vfb   = (float*)(ws + 109051904);            // 67,108,864 B
    unsigned short* rbb   = (unsigned short*)(ws + 176160768);   // 33,554,432 B
    unsigned short* rwkvb = (unsigned short*)(ws + 209715200);   // 33,554,432 B
    // segment/prefix state arrays alias the xb region (xb dead before phase1 runs)
    float* segA = (float*)(ws + 0);
    float* segB = (float*)(ws + 1048576);
    float* segP = (float*)(ws + 2097152);
    float* preA = (float*)(ws + 3145728);
    float* preB = (float*)(ws + 4194304);
    float* preP = (float*)(ws + 5242880);

    // casts to bf16
    castk<<<2048, 256, 0, stream>>>(x,  xb,  MDIM * CDIM / 4);
    castk<<<512,  256, 0, stream>>>(kw, kwb, CDIM * CDIM / 4);
    castk<<<512,  256, 0, stream>>>(vw, vwb, CDIM * CDIM / 4);
    castk<<<512,  256, 0, stream>>>(rw, rwb, CDIM * CDIM / 4);
    castk<<<512,  256, 0, stream>>>(ow, owb, CDIM * CDIM / 4);

    dim3 gg(MDIM / 128, CDIM / 128);
    gemm_bt<0><<<gg, 256, 0, stream>>>(xb, kwb, kfb, CDIM, CDIM);
    gemm_bt<0><<<gg, 256, 0, stream>>>(xb, vwb, vfb, CDIM, CDIM);
    gemm_bt<1><<<gg, 256, 0, stream>>>(xb, rwb, rbb, CDIM, CDIM);

    // segmented WKV scan (xb region reused for states from here on)
    wkv_phase1<<<NCH * SSEG / 256, 256, 0, stream>>>(kfb, vfb, td, segA, segB, segP);
    wkv_phase2<<<NCH / 256, 256, 0, stream>>>(segA, segB, segP, td, aa0, bb0, pp0,
                                              preA, preB, preP, out + (size_t)MDIM * CDIM);
    wkv_phase3<<<NCH * SSEG / 256, 256, 0, stream>>>(kfb, vfb, rbb, td, tf,
                                                     preA, preB, preP, rwkvb);

    gemm_bt<0><<<gg, 256, 0, stream>>>(rwkvb, owb, out, CDIM, CDIM);
}

// Round 3
// 245.818 us; speedup vs baseline: 3.0434x; 1.0866x over previous
//
#include <hip/hip_runtime.h>
#include <stdint.h>

#define BDIM 4
#define TDIM 4096
#define CDIM 1024
#define MDIM (BDIM * TDIM) // 16384
#define SSEG 64            // segments along T
#define LSEG 64            // steps per segment
#define NCH  (BDIM * CDIM) // 4096 channels

#define GK   1024          // GEMM K (both GEMMs)
#define GK2  2048          // K row stride in bytes (bf16)
#define NTK  16            // K-tiles of 64
#define NT4  64            // half-tiles total (4 per K-tile)

typedef __attribute__((ext_vector_type(8))) short bf16x8;
typedef __attribute__((ext_vector_type(4))) float f32x4;

__device__ __forceinline__ unsigned short f2bf(float f) {
    unsigned u = __builtin_bit_cast(unsigned, f);
    u = u + 0x7fffu + ((u >> 16) & 1u); // RNE
    return (unsigned short)(u >> 16);
}
__device__ __forceinline__ float bf2f(unsigned short h) {
    unsigned u = ((unsigned)h) << 16;
    return __builtin_bit_cast(float, u);
}

typedef __attribute__((address_space(1))) const unsigned int g_u32;
typedef __attribute__((address_space(3))) unsigned int l_u32;
__device__ __forceinline__ void gload_lds16(const void* g, void* l) {
    __builtin_amdgcn_global_load_lds((g_u32*)g, (l_u32*)l, 16, 0, 0);
}

// ---------------- fp32 -> bf16 cast (vectorized) ----------------
__global__ void castk(const float* __restrict__ src, unsigned short* __restrict__ dst, int n4) {
    int i = blockIdx.x * blockDim.x + threadIdx.x;
    int stride = gridDim.x * blockDim.x;
    for (int j = i; j < n4; j += stride) {
        float4 f = ((const float4*)src)[j];
        ushort4 o;
        o.x = f2bf(f.x); o.y = f2bf(f.y); o.z = f2bf(f.z); o.w = f2bf(f.w);
        ((ushort4*)dst)[j] = o;
    }
}

// ---------------- 256x256 8-phase bf16 GEMM (Y = A * Bw^T) ----------------
// A [M,1024] bf16, Bw [N,1024] bf16 (row-major, dot over rows of both).
// 512 threads = 8 waves (2M x 4N). BK=64, 2 LDS slots (K-tile level dbuf),
// halves staged B0,B1,A0,A1 per tile, skew-7 stage stream, vmcnt(6) counted
// waits at q3 only, XOR swizzle byte^=((row&7)<<4) both-sides.
// MODE 0: fused QKV epilogue -> oK/oV(bf16), oR(sigmoid,bf16), widths 1024.
// MODE 1: fp32 store to oF, width 1024.
template <int MODE>
__global__ __launch_bounds__(512, 2) void gemm256(
    const unsigned short* __restrict__ A,
    const unsigned short* __restrict__ Bw,
    unsigned short* __restrict__ oK, unsigned short* __restrict__ oV,
    unsigned short* __restrict__ oR, float* __restrict__ oF)
{
    extern __shared__ char sh[];
    char* shA = sh;             // 2 slots x 2 halves x 16384 B
    char* shB = sh + 65536;

    const int tid  = threadIdx.x;
    const int wave = tid >> 6;
    const int lane = tid & 63;
    const int wm   = wave >> 2;      // 0..1 (M half)
    const int wn   = wave & 3;       // 0..3 (N quarter)
    const int lrow = lane & 15;
    const int koct = lane >> 4;      // 0..3

    // XCD-aware block swizzle (grid % 8 == 0 for both call sites)
    const int nwg = gridDim.x;
    const int cpx = nwg >> 3;
    const int bid = blockIdx.x;
    const int wg  = (bid & 7) * cpx + (bid >> 3);
    const int mt  = wg & 63;         // M/256 = 64 tiles, mt-fast
    const int nt  = wg >> 6;
    const size_t row0 = (size_t)mt * 256;
    const size_t col0 = (size_t)nt * 256;

    const char* gA = (const char*)A  + row0 * GK2;
    const char* gB = (const char*)Bw + col0 * GK2;

    // stage one half-tile h: tile t=h>>2; parts: 0=B half0,1=B half1,2=A half0,3=A half1
    auto stage_half = [&](int h) {
        if (h >= NT4) return;
        int t = h >> 2, part = h & 3, slot = t & 1;
        int isA = part >> 1, half = part & 1;
        const char* gbase = isA ? gA : gB;
        char* lbase = (isA ? shA : shB) + (slot * 2 + half) * 16384;
#pragma unroll
        for (int j = 0; j < 2; ++j) {
            int d = (j * 512 + tid) * 16;
            int r = d >> 7;
            int cb = (d & 127) ^ ((r & 7) << 4);  // inverse-swizzled source
            gload_lds16(gbase + (size_t)(half * 128 + r) * GK2 + t * 128 + cb, lbase + d);
        }
    };

    // prologue: 7 half-tiles (t0 fully + B0,B1,A0 of t1), drain to 3 in flight
#pragma unroll
    for (int h = 0; h < 7; ++h) stage_half(h);
    asm volatile("s_waitcnt vmcnt(6)" ::: "memory");
    asm volatile("s_barrier" ::: "memory");

    f32x4 acc[8][4] = {};
    bf16x8 afr[8][2], bfr[4][2];

    for (int t = 0; t < NTK; ++t) {
        const int slot = t & 1;
        const int aoff = (slot * 2 + wm) * 16384;
        const int boff = (slot * 2 + (wn >> 1)) * 16384;
        const int brb  = (wn & 1) * 64;

        // ---- phase q0: read A-mh0 (8) + all B (8); stage t+1 A1; MFMA (mh0,nh0)
#pragma unroll
        for (int mi = 0; mi < 4; ++mi) {
            int r = mi * 16 + lrow, sw = (r & 7) << 4;
#pragma unroll
            for (int ks = 0; ks < 2; ++ks)
                afr[mi][ks] = *(const bf16x8*)(shA + aoff + r * 128 + ((ks * 64 + koct * 16) ^ sw));
        }
#pragma unroll
        for (int ni = 0; ni < 4; ++ni) {
            int r = brb + ni * 16 + lrow, sw = (r & 7) << 4;
#pragma unroll
            for (int ks = 0; ks < 2; ++ks)
                bfr[ni][ks] = *(const bf16x8*)(shB + boff + r * 128 + ((ks * 64 + koct * 16) ^ sw));
        }
        stage_half(4 * t + 7);
        asm volatile("s_barrier" ::: "memory");
        __builtin_amdgcn_s_setprio(1);
#pragma unroll
        for (int a = 0; a < 4; ++a)
#pragma unroll
            for (int b = 0; b < 2; ++b)
#pragma unroll
                for (int ks = 0; ks < 2; ++ks)
                    acc[a][b] = __builtin_amdgcn_mfma_f32_16x16x32_bf16(afr[a][ks], bfr[b][ks], acc[a][b], 0, 0, 0);
        __builtin_amdgcn_s_setprio(0);
        asm volatile("s_barrier" ::: "memory");

        // ---- phase q1: read A-mh1 (8); stage t+2 B0; MFMA (mh0,nh1)
#pragma unroll
        for (int mi = 4; mi < 8; ++mi) {
            int r = mi * 16 + lrow, sw = (r & 7) << 4;
#pragma unroll
            for (int ks = 0; ks < 2; ++ks)
                afr[mi][ks] = *(const bf16x8*)(shA + aoff + r * 128 + ((ks * 64 + koct * 16) ^ sw));
        }
        stage_half(4 * t + 8);
        asm volatile("s_barrier" ::: "memory");
        __builtin_amdgcn_s_setprio(1);
#pragma unroll
        for (int a = 0; a < 4; ++a)
#pragma unroll
            for (int b = 0; b < 2; ++b)
#pragma unroll
                for (int ks = 0; ks < 2; ++ks)
                    acc[a][2 + b] = __builtin_amdgcn_mfma_f32_16x16x32_bf16(afr[a][ks], bfr[2 + b][ks], acc[a][2 + b], 0, 0, 0);
        __builtin_amdgcn_s_setprio(0);
        asm volatile("s_barrier" ::: "memory");

        // ---- phase q2: stage t+2 B1; MFMA (mh1,nh0)
        stage_half(4 * t + 9);
        asm volatile("s_barrier" ::: "memory");
        __builtin_amdgcn_s_setprio(1);
#pragma unroll
        for (int a = 0; a < 4; ++a)
#pragma unroll
            for (int b = 0; b < 2; ++b)
#pragma unroll
                for (int ks = 0; ks < 2; ++ks)
                    acc[4 + a][b] = __builtin_amdgcn_mfma_f32_16x16x32_bf16(afr[4 + a][ks], bfr[b][ks], acc[4 + a][b], 0, 0, 0);
        __builtin_amdgcn_s_setprio(0);
        asm volatile("s_barrier" ::: "memory");

        // ---- phase q3: stage t+2 A0; MFMA (mh1,nh1); counted vmcnt; barrier
        stage_half(4 * t + 10);
        asm volatile("s_barrier" ::: "memory");
        __builtin_amdgcn_s_setprio(1);
#pragma unroll
        for (int a = 0; a < 4; ++a)
#pragma unroll
            for (int b = 0; b < 2; ++b)
#pragma unroll
                for (int ks = 0; ks < 2; ++ks)
                    acc[4 + a][2 + b] = __builtin_amdgcn_mfma_f32_16x16x32_bf16(afr[4 + a][ks], bfr[2 + b][ks], acc[4 + a][2 + b], 0, 0, 0);
        __builtin_amdgcn_s_setprio(0);
        if (t < NTK - 2)       asm volatile("s_waitcnt vmcnt(6)" ::: "memory");
        else if (t == NTK - 2) asm volatile("s_waitcnt vmcnt(0)" ::: "memory");
        asm volatile("s_barrier" ::: "memory");
    }

    // ---- epilogue: C/D frag layout col=lane&15, row=(lane>>4)*4+j
    const int crow = (lane >> 4) * 4;
    const int ccol = lane & 15;
    if (MODE == 1) {
#pragma unroll
        for (int mi = 0; mi < 8; ++mi)
#pragma unroll
            for (int ni = 0; ni < 4; ++ni) {
                size_t gr = row0 + wm * 128 + mi * 16 + crow;
                size_t gc = col0 + wn * 64 + ni * 16 + ccol;
#pragma unroll
                for (int j = 0; j < 4; ++j)
                    oF[(gr + j) * 1024 + gc] = acc[mi][ni][j];
            }
    } else {
        const int region = nt >> 2;  // 0=K, 1=V, 2=R
        unsigned short* dst = (region == 0) ? oK : ((region == 1) ? oV : oR);
        const size_t cb0 = (size_t)(nt & 3) * 256;
#pragma unroll
        for (int mi = 0; mi < 8; ++mi)
#pragma unroll
            for (int ni = 0; ni < 4; ++ni) {
                size_t gr = row0 + wm * 128 + mi * 16 + crow;
                size_t gc = cb0 + wn * 64 + ni * 16 + ccol;
#pragma unroll
                for (int j = 0; j < 4; ++j) {
                    float val = acc[mi][ni][j];
                    if (region == 2) val = 1.0f / (1.0f + __expf(-val));
                    dst[(gr + j) * 1024 + gc] = f2bf(val);
                }
            }
    }
}

// ---------------- WKV segmented scan (bf16 k,v,r) ----------------
__global__ __launch_bounds__(256) void wkv_phase1(
    const unsigned short* __restrict__ kf, const unsigned short* __restrict__ vf,
    const float* __restrict__ td,
    float* __restrict__ segA, float* __restrict__ segB, float* __restrict__ segP)
{
    const int tid  = blockIdx.x * 256 + threadIdx.x;
    const int lane = tid & 63;
    const int wg   = tid >> 6;
    const int cg   = wg & 63;
    const int s    = wg >> 6;
    const int q    = cg * 64 + lane;
    const int b    = q >> 10;
    const int c    = q & (CDIM - 1);

    const float w = __expf(td[c]);

    float aa = 0.0f, bb = 0.0f, pp = -1e38f;
    size_t idx = (size_t)b * TDIM * CDIM + (size_t)(s * LSEG) * CDIM + c;
#pragma unroll 4
    for (int i = 0; i < LSEG; ++i, idx += CDIM) {
        float kt = bf2f(kf[idx]);
        float vt = bf2f(vf[idx]);
        float ww2 = pp - w;
        float p2  = fmaxf(ww2, kt);
        float e1  = __expf(ww2 - p2);
        float e2  = __expf(kt - p2);
        aa = e1 * aa + e2 * vt;
        bb = e1 * bb + e2;
        pp = p2;
    }
    segA[s * NCH + q] = aa;
    segB[s * NCH + q] = bb;
    segP[s * NCH + q] = pp;
}

__global__ __launch_bounds__(256) void wkv_phase2(
    const float* __restrict__ segA, const float* __restrict__ segB, const float* __restrict__ segP,
    const float* __restrict__ td,
    const float* __restrict__ aa0, const float* __restrict__ bb0, const float* __restrict__ pp0,
    float* __restrict__ preA, float* __restrict__ preB, float* __restrict__ preP,
    float* __restrict__ stout)
{
    const int tid = blockIdx.x * 256 + threadIdx.x;   // 0..NCH-1
    const int c = tid & (CDIM - 1);
    const float w  = __expf(td[c]);
    const float Lw = (float)LSEG * w;

    float aa = aa0[tid], bb = bb0[tid], pp = pp0[tid];
    for (int s = 0; s < SSEG; ++s) {
        preA[s * NCH + tid] = aa;
        preB[s * NCH + tid] = bb;
        preP[s * NCH + tid] = pp;
        float al = segA[s * NCH + tid];
        float bl = segB[s * NCH + tid];
        float pl = segP[s * NCH + tid];
        float ppd = pp - Lw;
        float p  = fmaxf(ppd, pl);
        float e1 = __expf(ppd - p);
        float e2 = __expf(pl - p);
        aa = e1 * aa + e2 * al;
        bb = e1 * bb + e2 * bl;
        pp = p;
    }
    stout[tid]           = aa;
    stout[NCH + tid]     = bb;
    stout[2 * NCH + tid] = pp;
}

__global__ __launch_bounds__(256) void wkv_phase3(
    const unsigned short* __restrict__ kf, const unsigned short* __restrict__ vf,
    const unsigned short* __restrict__ rb,
    const float* __restrict__ td, const float* __restrict__ tf,
    const float* __restrict__ preA, const float* __restrict__ preB, const float* __restrict__ preP,
    unsigned short* __restrict__ rwkvb)
{
    const int tid  = blockIdx.x * 256 + threadIdx.x;
    const int lane = tid & 63;
    const int wg   = tid >> 6;
    const int cg   = wg & 63;
    const int s    = wg >> 6;
    const int q    = cg * 64 + lane;
    const int b    = q >> 10;
    const int c    = q & (CDIM - 1);

    const float w = __expf(td[c]);
    const float u = tf[c];

    float aa = preA[s * NCH + q];
    float bb = preB[s * NCH + q];
    float pp = preP[s * NCH + q];

    size_t idx = (size_t)b * TDIM * CDIM + (size_t)(s * LSEG) * CDIM + c;
#pragma unroll 4
    for (int i = 0; i < LSEG; ++i, idx += CDIM) {
        float kt = bf2f(kf[idx]);
        float vt = bf2f(vf[idx]);
        float rt = bf2f(rb[idx]);
        float ww = u + kt;
        float p  = fmaxf(pp, ww);
        float e1 = __expf(pp - p);
        float e2 = __expf(ww - p);
        float wkv = (e1 * aa + e2 * vt) / (e1 * bb + e2);
        rwkvb[idx] = f2bf(rt * wkv);
        float ww2 = pp - w;
        float p2  = fmaxf(ww2, kt);
        float e1b = __expf(ww2 - p2);
        float e2b = __expf(kt - p2);
        aa = e1b * aa + e2b * vt;
        bb = e1b * bb + e2b;
        pp = p2;
    }
}

extern "C" void kernel_launch(void* const* d_in, const int* in_sizes, int n_in,
                              void* d_out, int out_size, void* d_ws, size_t ws_size,
                              hipStream_t stream) {
    const float* x   = (const float*)d_in[0];
    const float* kw  = (const float*)d_in[1];
    const float* vw  = (const float*)d_in[2];
    const float* rw  = (const float*)d_in[3];
    const float* ow  = (const float*)d_in[4];
    const float* td  = (const float*)d_in[5];
    const float* tf  = (const float*)d_in[6];
    const float* aa0 = (const float*)d_in[7];
    const float* bb0 = (const float*)d_in[8];
    const float* pp0 = (const float*)d_in[9];
    float* out = (float*)d_out;

    char* ws = (char*)d_ws;
    unsigned short* wf    = (unsigned short*)(ws);               //  6,291,456 B  [3072][1024] bf16 (K,V,R weights)
    unsigned short* owb   = (unsigned short*)(ws + 6291456);     //  2,097,152 B
    unsigned short* xb    = (unsigned short*)(ws + 8388608);     // 33,554,432 B
    unsigned short* kfb   = (unsigned short*)(ws + 41943040);    // 33,554,432 B (bf16 now)
    unsigned short* vfb   = (unsigned short*)(ws + 75497472);    // 33,554,432 B
    unsigned short* rbb   = (unsigned short*)(ws + 109051904);   // 33,554,432 B
    unsigned short* rwkvb = (unsigned short*)(ws + 142606336);   // 33,554,432 B
    float* segA = (float*)(ws + 176160768);
    float* segB = (float*)(ws + 177209344);
    float* segP = (float*)(ws + 178257920);
    float* preA = (float*)(ws + 179306496);
    float* preB = (float*)(ws + 180355072);
    float* preP = (float*)(ws + 181403648);
    // total ws use: ~182.5 MB

    hipFuncSetAttribute((const void*)gemm256<0>, hipFuncAttributeMaxDynamicSharedMemorySize, 131072);
    hipFuncSetAttribute((const void*)gemm256<1>, hipFuncAttributeMaxDynamicSharedMemorySize, 131072);

    // casts to bf16 (weights concatenated K,V,R for the fused GEMM)
    castk<<<2048, 256, 0, stream>>>(x,  xb, MDIM * CDIM / 4);
    castk<<<512,  256, 0, stream>>>(kw, wf,            CDIM * CDIM / 4);
    castk<<<512,  256, 0, stream>>>(vw, wf + 1048576,  CDIM * CDIM / 4);
    castk<<<512,  256, 0, stream>>>(rw, wf + 2097152,  CDIM * CDIM / 4);
    castk<<<512,  256, 0, stream>>>(ow, owb,           CDIM * CDIM / 4);

    // fused QKV projection: [16384,1024] x [3072,1024]^T, 64x12=768 blocks
    gemm256<0><<<768, 512, 131072, stream>>>(xb, wf, kfb, vfb, rbb, nullptr);

    // segmented WKV scan
    wkv_phase1<<<NCH * SSEG / 256, 256, 0, stream>>>(kfb, vfb, td, segA, segB, segP);
    wkv_phase2<<<NCH / 256, 256, 0, stream>>>(segA, segB, segP, td, aa0, bb0, pp0,
                                              preA, preB, preP, out + (size_t)MDIM * CDIM);
    wkv_phase3<<<NCH * SSEG / 256, 256, 0, stream>>>(kfb, vfb, rbb, td, tf,
                                                     preA, preB, preP, rwkvb);

    // output projection: [16384,1024] x [1024,1024]^T -> fp32 d_out, 64x4=256 blocks
    gemm256<1><<<256, 512, 131072, stream>>>(rwkvb, owb, nullptr, nullptr, nullptr, out);
}

// Round 4
// 241.271 us; speedup vs baseline: 3.1008x; 1.0188x over previous
//
#include <hip/hip_runtime.h>
#include <stdint.h>

#define BDIM 4
#define TDIM 4096
#define CDIM 1024
#define MDIM (BDIM * TDIM) // 16384
#define SSEG 64            // segments along T
#define LSEG 64            // steps per segment
#define NCH  (BDIM * CDIM) // 4096 channels

#define GK   1024          // GEMM K
#define GK2  2048          // K row stride in bytes (bf16)
#define NTK  16            // K-tiles of 64

typedef __attribute__((ext_vector_type(8))) short bf16x8;
typedef __attribute__((ext_vector_type(4))) float f32x4;

__device__ __forceinline__ unsigned short f2bf(float f) {
    unsigned u = __builtin_bit_cast(unsigned, f);
    u = u + 0x7fffu + ((u >> 16) & 1u); // RNE
    return (unsigned short)(u >> 16);
}
__device__ __forceinline__ float bf2f(unsigned short h) {
    unsigned u = ((unsigned)h) << 16;
    return __builtin_bit_cast(float, u);
}

typedef __attribute__((address_space(1))) const unsigned int g_u32;
typedef __attribute__((address_space(3))) unsigned int l_u32;
__device__ __forceinline__ void gload_lds16(const void* g, void* l) {
    __builtin_amdgcn_global_load_lds((g_u32*)g, (l_u32*)l, 16, 0, 0);
}

// ---------------- fp32 -> bf16 cast (vectorized) ----------------
__global__ void castk(const float* __restrict__ src, unsigned short* __restrict__ dst, int n4) {
    int i = blockIdx.x * blockDim.x + threadIdx.x;
    int stride = gridDim.x * blockDim.x;
    for (int j = i; j < n4; j += stride) {
        float4 f = ((const float4*)src)[j];
        ushort4 o;
        o.x = f2bf(f.x); o.y = f2bf(f.y); o.z = f2bf(f.z); o.w = f2bf(f.w);
        ((ushort4*)dst)[j] = o;
    }
}

// all 4 weight matrices in one launch (each 1M elems = 262144 float4)
__global__ void castw(const float* __restrict__ kw, const float* __restrict__ vw,
                      const float* __restrict__ rw, const float* __restrict__ ow,
                      unsigned short* __restrict__ wf, unsigned short* __restrict__ owb) {
    int i = blockIdx.x * 256 + threadIdx.x;
    int m = i >> 18, j = i & 262143;
    const float* s = (m == 0) ? kw : (m == 1) ? vw : (m == 2) ? rw : ow;
    unsigned short* d = (m < 3) ? (wf + (size_t)m * 1048576) : owb;
    float4 f = ((const float4*)s)[j];
    ushort4 o;
    o.x = f2bf(f.x); o.y = f2bf(f.y); o.z = f2bf(f.z); o.w = f2bf(f.w);
    ((ushort4*)d)[j] = o;
}

// ---------------- 256x256 8-phase bf16 GEMM (Y = A * Bw^T) ----------------
// 512 threads = 8 waves (2M x 4N). BK=64, 2 LDS slots, 1 half-tile staged per
// phase (q0:B0_{t+1} q1:B1_{t+1} q2:A0_{t+2} q3:A1_{t+2}), reads balanced
// (q0: bfr x8, q1: afr[4..7] x8, q2: none, q3: afr[0..3] of t+1 x8),
// counted vmcnt(6)@q2-end / vmcnt(4)@q3-end, XOR swizzle both-sides.
// MODE 0: fused QKV epilogue -> oK/oV(bf16), oR(sigmoid,bf16). MODE 1: fp32.
template <int MODE>
__global__ __launch_bounds__(512, 2) void gemm256(
    const unsigned short* __restrict__ A,
    const unsigned short* __restrict__ Bw,
    unsigned short* __restrict__ oK, unsigned short* __restrict__ oV,
    unsigned short* __restrict__ oR, float* __restrict__ oF)
{
    extern __shared__ char sh[];
    char* shA = sh;             // 2 slots x 2 halves x 16384 B
    char* shB = sh + 65536;

    const int tid  = threadIdx.x;
    const int wave = tid >> 6;
    const int lane = tid & 63;
    const int wm   = wave >> 2;      // 0..1 (M half)
    const int wn   = wave & 3;       // 0..3 (N quarter)
    const int lrow = lane & 15;
    const int koct = lane >> 4;      // 0..3

    // XCD-aware block swizzle (grid % 8 == 0 at both call sites)
    const int nwg = gridDim.x;
    const int cpx = nwg >> 3;
    const int bid = blockIdx.x;
    const int wg  = (bid & 7) * cpx + (bid >> 3);
    const int mt  = wg & 63;
    const int nt  = wg >> 6;
    const size_t row0 = (size_t)mt * 256;
    const size_t col0 = (size_t)nt * 256;

    const char* gA = (const char*)A  + row0 * GK2;
    const char* gB = (const char*)Bw + col0 * GK2;

    // stage one half-tile of tile tt; part: 0=A half0, 1=A half1, 2=B half0, 3=B half1
    auto stage = [&](int tt, int part) {
        if (tt >= NTK) return;
        int slot = tt & 1;
        int isA  = (part < 2) ? 1 : 0;
        int half = part & 1;
        const char* gbase = isA ? gA : gB;
        char* lbase = (isA ? shA : shB) + (slot * 2 + half) * 16384;
#pragma unroll
        for (int j = 0; j < 2; ++j) {
            int d = (j * 512 + tid) * 16;
            int r = d >> 7;
            int cb = (d & 127) ^ ((r & 7) << 4);  // inverse-swizzled source
            gload_lds16(gbase + (size_t)(half * 128 + r) * GK2 + tt * 128 + cb, lbase + d);
        }
    };

    // prologue: tile0 (A0,A1,B0,B1) + tile1 (A0,A1) = 6 halves, 12 loads/thread
    stage(0, 0); stage(0, 1); stage(0, 2); stage(0, 3);
    stage(1, 0); stage(1, 1);
    asm volatile("s_waitcnt vmcnt(4)" ::: "memory");   // tile0 fully resident
    asm volatile("s_barrier" ::: "memory");

    f32x4 acc[8][4] = {};
    bf16x8 afr[8], bfr[4];          // [frag] each holding 2 ks? -> use [frag][ks]
    bf16x8 afr2[8][1];              // (unused placeholder removed below)
    (void)afr2;
    bf16x8 af[8][2], bf_[4][2];

    // pre-read afr[0..3] of tile 0 (slot 0)
    {
        const int aoff = (0 * 2 + wm) * 16384;
#pragma unroll
        for (int mi = 0; mi < 4; ++mi) {
            int r = mi * 16 + lrow, sw = (r & 7) << 4;
#pragma unroll
            for (int ks = 0; ks < 2; ++ks)
                af[mi][ks] = *(const bf16x8*)(shA + aoff + r * 128 + ((ks * 64 + koct * 16) ^ sw));
        }
    }

    for (int t = 0; t < NTK; ++t) {
        const int slot  = t & 1;
        const int aoff  = (slot * 2 + wm) * 16384;
        const int boff  = (slot * 2 + (wn >> 1)) * 16384;
        const int brb   = (wn & 1) * 64;
        const int slotN = (t + 1) & 1;
        const int aoffN = (slotN * 2 + wm) * 16384;

        // ---- q0: stage B0_{t+1}; read bfr[0..3]; MFMA (mh0,nh0)
        stage(t + 1, 2);
#pragma unroll
        for (int ni = 0; ni < 4; ++ni) {
            int r = brb + ni * 16 + lrow, sw = (r & 7) << 4;
#pragma unroll
            for (int ks = 0; ks < 2; ++ks)
                bf_[ni][ks] = *(const bf16x8*)(shB + boff + r * 128 + ((ks * 64 + koct * 16) ^ sw));
        }
        asm volatile("s_barrier" ::: "memory");
        __builtin_amdgcn_s_setprio(1);
#pragma unroll
        for (int a = 0; a < 4; ++a)
#pragma unroll
            for (int b = 0; b < 2; ++b)
#pragma unroll
                for (int ks = 0; ks < 2; ++ks)
                    acc[a][b] = __builtin_amdgcn_mfma_f32_16x16x32_bf16(af[a][ks], bf_[b][ks], acc[a][b], 0, 0, 0);
        __builtin_amdgcn_s_setprio(0);
        asm volatile("s_barrier" ::: "memory");

        // ---- q1: stage B1_{t+1}; read afr[4..7]; MFMA (mh0,nh1)
        stage(t + 1, 3);
#pragma unroll
        for (int mi = 4; mi < 8; ++mi) {
            int r = mi * 16 + lrow, sw = (r & 7) << 4;
#pragma unroll
            for (int ks = 0; ks < 2; ++ks)
                af[mi][ks] = *(const bf16x8*)(shA + aoff + r * 128 + ((ks * 64 + koct * 16) ^ sw));
        }
        asm volatile("s_barrier" ::: "memory");
        __builtin_amdgcn_s_setprio(1);
#pragma unroll
        for (int a = 0; a < 4; ++a)
#pragma unroll
            for (int b = 0; b < 2; ++b)
#pragma unroll
                for (int ks = 0; ks < 2; ++ks)
                    acc[a][2 + b] = __builtin_amdgcn_mfma_f32_16x16x32_bf16(af[a][ks], bf_[2 + b][ks], acc[a][2 + b], 0, 0, 0);
        __builtin_amdgcn_s_setprio(0);
        asm volatile("s_barrier" ::: "memory");

        // ---- q2: stage A0_{t+2}; no reads; MFMA (mh1,nh0); vmcnt for q3 prefetch
        stage(t + 2, 0);
        asm volatile("s_barrier" ::: "memory");
        __builtin_amdgcn_s_setprio(1);
#pragma unroll
        for (int a = 0; a < 4; ++a)
#pragma unroll
            for (int b = 0; b < 2; ++b)
#pragma unroll
                for (int ks = 0; ks < 2; ++ks)
                    acc[4 + a][b] = __builtin_amdgcn_mfma_f32_16x16x32_bf16(af[4 + a][ks], bf_[b][ks], acc[4 + a][b], 0, 0, 0);
        __builtin_amdgcn_s_setprio(0);
        if (t <= 13)      asm volatile("s_waitcnt vmcnt(6)" ::: "memory"); // A1_{t+1} resident
        else if (t == 14) asm volatile("s_waitcnt vmcnt(4)" ::: "memory");
        asm volatile("s_barrier" ::: "memory");

        // ---- q3: stage A1_{t+2}; prefetch afr[0..3] of t+1; MFMA (mh1,nh1); vmcnt for next q0
        stage(t + 2, 1);
        if (t + 1 < NTK) {
#pragma unroll
            for (int mi = 0; mi < 4; ++mi) {
                int r = mi * 16 + lrow, sw = (r & 7) << 4;
#pragma unroll
                for (int ks = 0; ks < 2; ++ks)
                    af[mi][ks] = *(const bf16x8*)(shA + aoffN + r * 128 + ((ks * 64 + koct * 16) ^ sw));
            }
        }
        asm volatile("s_barrier" ::: "memory");
        __builtin_amdgcn_s_setprio(1);
#pragma unroll
        for (int a = 0; a < 4; ++a)
#pragma unroll
            for (int b = 0; b < 2; ++b)
#pragma unroll
                for (int ks = 0; ks < 2; ++ks)
                    acc[4 + a][2 + b] = __builtin_amdgcn_mfma_f32_16x16x32_bf16(af[4 + a][ks], bf_[2 + b][ks], acc[4 + a][2 + b], 0, 0, 0);
        __builtin_amdgcn_s_setprio(0);
        if (t <= 13)      asm volatile("s_waitcnt vmcnt(4)" ::: "memory"); // B1_{t+1} resident
        else if (t == 14) asm volatile("s_waitcnt vmcnt(0)" ::: "memory");
        asm volatile("s_barrier" ::: "memory");
    }

    // ---- epilogue: C/D frag layout col=lane&15, row=(lane>>4)*4+j
    const int crow = (lane >> 4) * 4;
    const int ccol = lane & 15;
    if (MODE == 1) {
#pragma unroll
        for (int mi = 0; mi < 8; ++mi)
#pragma unroll
            for (int ni = 0; ni < 4; ++ni) {
                size_t gr = row0 + wm * 128 + mi * 16 + crow;
                size_t gc = col0 + wn * 64 + ni * 16 + ccol;
#pragma unroll
                for (int j = 0; j < 4; ++j)
                    oF[(gr + j) * 1024 + gc] = acc[mi][ni][j];
            }
    } else {
        const int region = nt >> 2;  // 0=K, 1=V, 2=R
        unsigned short* dst = (region == 0) ? oK : ((region == 1) ? oV : oR);
        const size_t cb0 = (size_t)(nt & 3) * 256;
#pragma unroll
        for (int mi = 0; mi < 8; ++mi)
#pragma unroll
            for (int ni = 0; ni < 4; ++ni) {
                size_t gr = row0 + wm * 128 + mi * 16 + crow;
                size_t gc = cb0 + wn * 64 + ni * 16 + ccol;
#pragma unroll
                for (int j = 0; j < 4; ++j) {
                    float val = acc[mi][ni][j];
                    if (region == 2) val = 1.0f / (1.0f + __expf(-val));
                    dst[(gr + j) * 1024 + gc] = f2bf(val);
                }
            }
    }
}

// ---------------- WKV segmented scan (bf16 k,v,r) ----------------
__global__ __launch_bounds__(256) void wkv_phase1(
    const unsigned short* __restrict__ kf, const unsigned short* __restrict__ vf,
    const float* __restrict__ td,
    float* __restrict__ segA, float* __restrict__ segB, float* __restrict__ segP)
{
    const int tid  = blockIdx.x * 256 + threadIdx.x;
    const int lane = tid & 63;
    const int wg   = tid >> 6;
    const int cg   = wg & 63;
    const int s    = wg >> 6;
    const int q    = cg * 64 + lane;
    const int b    = q >> 10;
    const int c    = q & (CDIM - 1);

    const float w = __expf(td[c]);

    float aa = 0.0f, bb = 0.0f, pp = -1e38f;
    size_t idx = (size_t)b * TDIM * CDIM + (size_t)(s * LSEG) * CDIM + c;
#pragma unroll 4
    for (int i = 0; i < LSEG; ++i, idx += CDIM) {
        float kt = bf2f(kf[idx]);
        float vt = bf2f(vf[idx]);
        float ww2 = pp - w;
        float p2  = fmaxf(ww2, kt);
        float e1  = __expf(ww2 - p2);
        float e2  = __expf(kt - p2);
        aa = e1 * aa + e2 * vt;
        bb = e1 * bb + e2;
        pp = p2;
    }
    segA[s * NCH + q] = aa;
    segB[s * NCH + q] = bb;
    segP[s * NCH + q] = pp;
}

__global__ __launch_bounds__(256) void wkv_phase2(
    const float* __restrict__ segA, const float* __restrict__ segB, const float* __restrict__ segP,
    const float* __restrict__ td,
    const float* __restrict__ aa0, const float* __restrict__ bb0, const float* __restrict__ pp0,
    float* __restrict__ preA, float* __restrict__ preB, float* __restrict__ preP,
    float* __restrict__ stout)
{
    const int tid = blockIdx.x * 256 + threadIdx.x;   // 0..NCH-1
    const int c = tid & (CDIM - 1);
    const float w  = __expf(td[c]);
    const float Lw = (float)LSEG * w;

    float aa = aa0[tid], bb = bb0[tid], pp = pp0[tid];
    for (int s = 0; s < SSEG; ++s) {
        preA[s * NCH + tid] = aa;
        preB[s * NCH + tid] = bb;
        preP[s * NCH + tid] = pp;
        float al = segA[s * NCH + tid];
        float bl = segB[s * NCH + tid];
        float pl = segP[s * NCH + tid];
        float ppd = pp - Lw;
        float p  = fmaxf(ppd, pl);
        float e1 = __expf(ppd - p);
        float e2 = __expf(pl - p);
        aa = e1 * aa + e2 * al;
        bb = e1 * bb + e2 * bl;
        pp = p;
    }
    stout[tid]           = aa;
    stout[NCH + tid]     = bb;
    stout[2 * NCH + tid] = pp;
}

__global__ __launch_bounds__(256) void wkv_phase3(
    const unsigned short* __restrict__ kf, const unsigned short* __restrict__ vf,
    const unsigned short* __restrict__ rb,
    const float* __restrict__ td, const float* __restrict__ tf,
    const float* __restrict__ preA, const float* __restrict__ preB, const float* __restrict__ preP,
    unsigned short* __restrict__ rwkvb)
{
    const int tid  = blockIdx.x * 256 + threadIdx.x;
    const int lane = tid & 63;
    const int wg   = tid >> 6;
    const int cg   = wg & 63;
    const int s    = wg >> 6;
    const int q    = cg * 64 + lane;
    const int b    = q >> 10;
    const int c    = q & (CDIM - 1);

    const float w = __expf(td[c]);
    const float u = tf[c];

    float aa = preA[s * NCH + q];
    float bb = preB[s * NCH + q];
    float pp = preP[s * NCH + q];

    size_t idx = (size_t)b * TDIM * CDIM + (size_t)(s * LSEG) * CDIM + c;
#pragma unroll 4
    for (int i = 0; i < LSEG; ++i, idx += CDIM) {
        float kt = bf2f(kf[idx]);
        float vt = bf2f(vf[idx]);
        float rt = bf2f(rb[idx]);
        float ww = u + kt;
        float p  = fmaxf(pp, ww);
        float e1 = __expf(pp - p);
        float e2 = __expf(ww - p);
        float wkv = (e1 * aa + e2 * vt) / (e1 * bb + e2);
        rwkvb[idx] = f2bf(rt * wkv);
        float ww2 = pp - w;
        float p2  = fmaxf(ww2, kt);
        float e1b = __expf(ww2 - p2);
        float e2b = __expf(kt - p2);
        aa = e1b * aa + e2b * vt;
        bb = e1b * bb + e2b;
        pp = p2;
    }
}

extern "C" void kernel_launch(void* const* d_in, const int* in_sizes, int n_in,
                              void* d_out, int out_size, void* d_ws, size_t ws_size,
                              hipStream_t stream) {
    const float* x   = (const float*)d_in[0];
    const float* kw  = (const float*)d_in[1];
    const float* vw  = (const float*)d_in[2];
    const float* rw  = (const float*)d_in[3];
    const float* ow  = (const float*)d_in[4];
    const float* td  = (const float*)d_in[5];
    const float* tf  = (const float*)d_in[6];
    const float* aa0 = (const float*)d_in[7];
    const float* bb0 = (const float*)d_in[8];
    const float* pp0 = (const float*)d_in[9];
    float* out = (float*)d_out;

    char* ws = (char*)d_ws;
    unsigned short* wf    = (unsigned short*)(ws);               //  6,291,456 B  [3072][1024] bf16
    unsigned short* owb   = (unsigned short*)(ws + 6291456);     //  2,097,152 B
    unsigned short* xb    = (unsigned short*)(ws + 8388608);     // 33,554,432 B
    unsigned short* kfb   = (unsigned short*)(ws + 41943040);    // 33,554,432 B
    unsigned short* vfb   = (unsigned short*)(ws + 75497472);    // 33,554,432 B
    unsigned short* rbb   = (unsigned short*)(ws + 109051904);   // 33,554,432 B
    unsigned short* rwkvb = (unsigned short*)(ws + 142606336);   // 33,554,432 B
    float* segA = (float*)(ws + 176160768);
    float* segB = (float*)(ws + 177209344);
    float* segP = (float*)(ws + 178257920);
    float* preA = (float*)(ws + 179306496);
    float* preB = (float*)(ws + 180355072);
    float* preP = (float*)(ws + 181403648);

    hipFuncSetAttribute((const void*)gemm256<0>, hipFuncAttributeMaxDynamicSharedMemorySize, 131072);
    hipFuncSetAttribute((const void*)gemm256<1>, hipFuncAttributeMaxDynamicSharedMemorySize, 131072);

    // casts to bf16
    castk<<<2048, 256, 0, stream>>>(x, xb, MDIM * CDIM / 4);
    castw<<<4096, 256, 0, stream>>>(kw, vw, rw, ow, wf, owb);

    // fused QKV projection: [16384,1024] x [3072,1024]^T, 64x12=768 blocks
    gemm256<0><<<768, 512, 131072, stream>>>(xb, wf, kfb, vfb, rbb, nullptr);

    // segmented WKV scan
    wkv_phase1<<<NCH * SSEG / 256, 256, 0, stream>>>(kfb, vfb, td, segA, segB, segP);
    wkv_phase2<<<NCH / 256, 256, 0, stream>>>(segA, segB, segP, td, aa0, bb0, pp0,
                                              preA, preB, preP, out + (size_t)MDIM * CDIM);
    wkv_phase3<<<NCH * SSEG / 256, 256, 0, stream>>>(kfb, vfb, rbb, td, tf,
                                                     preA, preB, preP, rwkvb);

    // output projection: [16384,1024] x [1024,1024]^T -> fp32 d_out
    gemm256<1><<<256, 512, 131072, stream>>>(rwkvb, owb, nullptr, nullptr, nullptr, out);
}

// Round 5
// 226.522 us; speedup vs baseline: 3.3027x; 1.0651x over previous
//
#include <hip/hip_runtime.h>
#include <stdint.h>

#define BDIM 4
#define TDIM 4096
#define CDIM 1024
#define MDIM (BDIM * TDIM) // 16384
#define SSEG 64            // segments along T
#define LSEG 64            // steps per segment
#define NCH  (BDIM * CDIM) // 4096 channels

#define GK   1024          // GEMM K
#define GK2  2048          // K row stride in bytes (bf16)
#define NTK  16            // K-tiles of 64

typedef __attribute__((ext_vector_type(8))) short bf16x8;
typedef __attribute__((ext_vector_type(4))) float f32x4;

__device__ __forceinline__ unsigned short f2bf(float f) {
    unsigned u = __builtin_bit_cast(unsigned, f);
    u = u + 0x7fffu + ((u >> 16) & 1u); // RNE
    return (unsigned short)(u >> 16);
}
__device__ __forceinline__ float bf2f(unsigned short h) {
    unsigned u = ((unsigned)h) << 16;
    return __builtin_bit_cast(float, u);
}

typedef __attribute__((address_space(1))) const unsigned int g_u32;
typedef __attribute__((address_space(3))) unsigned int l_u32;
__device__ __forceinline__ void gload_lds16(const void* g, void* l) {
    __builtin_amdgcn_global_load_lds((g_u32*)g, (l_u32*)l, 16, 0, 0);
}

// ---------------- fp32 -> bf16 cast (vectorized) ----------------
__global__ void castk(const float* __restrict__ src, unsigned short* __restrict__ dst, int n4) {
    int i = blockIdx.x * blockDim.x + threadIdx.x;
    int stride = gridDim.x * blockDim.x;
    for (int j = i; j < n4; j += stride) {
        float4 f = ((const float4*)src)[j];
        ushort4 o;
        o.x = f2bf(f.x); o.y = f2bf(f.y); o.z = f2bf(f.z); o.w = f2bf(f.w);
        ((ushort4*)dst)[j] = o;
    }
}

// all 4 weight matrices in one launch (each 1M elems = 262144 float4)
__global__ void castw(const float* __restrict__ kw, const float* __restrict__ vw,
                      const float* __restrict__ rw, const float* __restrict__ ow,
                      unsigned short* __restrict__ wf, unsigned short* __restrict__ owb) {
    int i = blockIdx.x * 256 + threadIdx.x;
    int m = i >> 18, j = i & 262143;
    const float* s = (m == 0) ? kw : (m == 1) ? vw : (m == 2) ? rw : ow;
    unsigned short* d = (m < 3) ? (wf + (size_t)m * 1048576) : owb;
    float4 f = ((const float4*)s)[j];
    ushort4 o;
    o.x = f2bf(f.x); o.y = f2bf(f.y); o.z = f2bf(f.z); o.w = f2bf(f.w);
    ((ushort4*)d)[j] = o;
}

// ---------------- 256x256 8-phase bf16 GEMM (Y = A * Bw^T) ----------------
// 512 threads = 8 waves (2M x 4N). BK=64, 2 LDS slots, 1 half-tile staged per
// phase (q0:B0_{t+1} q1:B1_{t+1} q2:A0_{t+2} q3:A1_{t+2}), reads balanced,
// counted vmcnt(6)@q2-end / vmcnt(4)@q3-end, XOR swizzle both-sides.
// L2-locality XCD swizzle: each XCD owns a disjoint 8-panel slice of A
// (mt = xcd*8 + idx/NT), nt-fast within the XCD so A panels get 12x L2 reuse.
// MODE 0: fused QKV epilogue -> oK/oV(bf16), oR(sigmoid,bf16). MODE 1: fp32.
template <int MODE, int NT>
__global__ __launch_bounds__(512, 2) void gemm256(
    const unsigned short* __restrict__ A,
    const unsigned short* __restrict__ Bw,
    unsigned short* __restrict__ oK, unsigned short* __restrict__ oV,
    unsigned short* __restrict__ oR, float* __restrict__ oF)
{
    extern __shared__ char sh[];
    char* shA = sh;             // 2 slots x 2 halves x 16384 B
    char* shB = sh + 65536;

    const int tid  = threadIdx.x;
    const int wave = tid >> 6;
    const int lane = tid & 63;
    const int wm   = wave >> 2;      // 0..1 (M half)
    const int wn   = wave & 3;       // 0..3 (N quarter)
    const int lrow = lane & 15;
    const int koct = lane >> 4;      // 0..3

    // L2-locality XCD swizzle (grid = 8 * 8 * NT blocks)
    const int bid = blockIdx.x;
    const int xcd = bid & 7;
    const int idx = bid >> 3;            // 0 .. 8*NT-1, dispatch order within XCD
    const int mt  = xcd * 8 + idx / NT;  // disjoint A-slice per XCD
    const int nt  = idx % NT;            // nt-fast: A panel reused by NT consecutive blocks
    const size_t row0 = (size_t)mt * 256;
    const size_t col0 = (size_t)nt * 256;

    const char* gA = (const char*)A  + row0 * GK2;
    const char* gB = (const char*)Bw + col0 * GK2;

    // stage one half-tile of tile tt; part: 0=A half0, 1=A half1, 2=B half0, 3=B half1
    auto stage = [&](int tt, int part) {
        if (tt >= NTK) return;
        int slot = tt & 1;
        int isA  = (part < 2) ? 1 : 0;
        int half = part & 1;
        const char* gbase = isA ? gA : gB;
        char* lbase = (isA ? shA : shB) + (slot * 2 + half) * 16384;
#pragma unroll
        for (int j = 0; j < 2; ++j) {
            int d = (j * 512 + tid) * 16;
            int r = d >> 7;
            int cb = (d & 127) ^ ((r & 7) << 4);  // inverse-swizzled source
            gload_lds16(gbase + (size_t)(half * 128 + r) * GK2 + tt * 128 + cb, lbase + d);
        }
    };

    // prologue: tile0 (A0,A1,B0,B1) + tile1 (A0,A1) = 6 halves
    stage(0, 0); stage(0, 1); stage(0, 2); stage(0, 3);
    stage(1, 0); stage(1, 1);
    asm volatile("s_waitcnt vmcnt(4)" ::: "memory");   // tile0 fully resident
    asm volatile("s_barrier" ::: "memory");

    f32x4 acc[8][4] = {};
    bf16x8 af[8][2], bf_[4][2];

    // pre-read afr[0..3] of tile 0 (slot 0)
    {
        const int aoff = (0 * 2 + wm) * 16384;
#pragma unroll
        for (int mi = 0; mi < 4; ++mi) {
            int r = mi * 16 + lrow, sw = (r & 7) << 4;
#pragma unroll
            for (int ks = 0; ks < 2; ++ks)
                af[mi][ks] = *(const bf16x8*)(shA + aoff + r * 128 + ((ks * 64 + koct * 16) ^ sw));
        }
    }

    for (int t = 0; t < NTK; ++t) {
        const int slot  = t & 1;
        const int aoff  = (slot * 2 + wm) * 16384;
        const int boff  = (slot * 2 + (wn >> 1)) * 16384;
        const int brb   = (wn & 1) * 64;
        const int slotN = (t + 1) & 1;
        const int aoffN = (slotN * 2 + wm) * 16384;

        // ---- q0: stage B0_{t+1}; read bfr[0..3]; MFMA (mh0,nh0)
        stage(t + 1, 2);
#pragma unroll
        for (int ni = 0; ni < 4; ++ni) {
            int r = brb + ni * 16 + lrow, sw = (r & 7) << 4;
#pragma unroll
            for (int ks = 0; ks < 2; ++ks)
                bf_[ni][ks] = *(const bf16x8*)(shB + boff + r * 128 + ((ks * 64 + koct * 16) ^ sw));
        }
        asm volatile("s_barrier" ::: "memory");
        __builtin_amdgcn_s_setprio(1);
#pragma unroll
        for (int a = 0; a < 4; ++a)
#pragma unroll
            for (int b = 0; b < 2; ++b)
#pragma unroll
                for (int ks = 0; ks < 2; ++ks)
                    acc[a][b] = __builtin_amdgcn_mfma_f32_16x16x32_bf16(af[a][ks], bf_[b][ks], acc[a][b], 0, 0, 0);
        __builtin_amdgcn_s_setprio(0);
        asm volatile("s_barrier" ::: "memory");

        // ---- q1: stage B1_{t+1}; read afr[4..7]; MFMA (mh0,nh1)
        stage(t + 1, 3);
#pragma unroll
        for (int mi = 4; mi < 8; ++mi) {
            int r = mi * 16 + lrow, sw = (r & 7) << 4;
#pragma unroll
            for (int ks = 0; ks < 2; ++ks)
                af[mi][ks] = *(const bf16x8*)(shA + aoff + r * 128 + ((ks * 64 + koct * 16) ^ sw));
        }
        asm volatile("s_barrier" ::: "memory");
        __builtin_amdgcn_s_setprio(1);
#pragma unroll
        for (int a = 0; a < 4; ++a)
#pragma unroll
            for (int b = 0; b < 2; ++b)
#pragma unroll
                for (int ks = 0; ks < 2; ++ks)
                    acc[a][2 + b] = __builtin_amdgcn_mfma_f32_16x16x32_bf16(af[a][ks], bf_[2 + b][ks], acc[a][2 + b], 0, 0, 0);
        __builtin_amdgcn_s_setprio(0);
        asm volatile("s_barrier" ::: "memory");

        // ---- q2: stage A0_{t+2}; no reads; MFMA (mh1,nh0); vmcnt for q3 prefetch
        stage(t + 2, 0);
        asm volatile("s_barrier" ::: "memory");
        __builtin_amdgcn_s_setprio(1);
#pragma unroll
        for (int a = 0; a < 4; ++a)
#pragma unroll
            for (int b = 0; b < 2; ++b)
#pragma unroll
                for (int ks = 0; ks < 2; ++ks)
                    acc[4 + a][b] = __builtin_amdgcn_mfma_f32_16x16x32_bf16(af[4 + a][ks], bf_[b][ks], acc[4 + a][b], 0, 0, 0);
        __builtin_amdgcn_s_setprio(0);
        if (t <= 13)      asm volatile("s_waitcnt vmcnt(6)" ::: "memory"); // A1_{t+1} resident
        else if (t == 14) asm volatile("s_waitcnt vmcnt(4)" ::: "memory");
        asm volatile("s_barrier" ::: "memory");

        // ---- q3: stage A1_{t+2}; prefetch afr[0..3] of t+1; MFMA (mh1,nh1); vmcnt for next q0
        stage(t + 2, 1);
        if (t + 1 < NTK) {
#pragma unroll
            for (int mi = 0; mi < 4; ++mi) {
                int r = mi * 16 + lrow, sw = (r & 7) << 4;
#pragma unroll
                for (int ks = 0; ks < 2; ++ks)
                    af[mi][ks] = *(const bf16x8*)(shA + aoffN + r * 128 + ((ks * 64 + koct * 16) ^ sw));
            }
        }
        asm volatile("s_barrier" ::: "memory");
        __builtin_amdgcn_s_setprio(1);
#pragma unroll
        for (int a = 0; a < 4; ++a)
#pragma unroll
            for (int b = 0; b < 2; ++b)
#pragma unroll
                for (int ks = 0; ks < 2; ++ks)
                    acc[4 + a][2 + b] = __builtin_amdgcn_mfma_f32_16x16x32_bf16(af[4 + a][ks], bf_[2 + b][ks], acc[4 + a][2 + b], 0, 0, 0);
        __builtin_amdgcn_s_setprio(0);
        if (t <= 13)      asm volatile("s_waitcnt vmcnt(4)" ::: "memory"); // B1_{t+1} resident
        else if (t == 14) asm volatile("s_waitcnt vmcnt(0)" ::: "memory");
        asm volatile("s_barrier" ::: "memory");
    }

    // ---- epilogue: C/D frag layout col=lane&15, row=(lane>>4)*4+j
    const int crow = (lane >> 4) * 4;
    const int ccol = lane & 15;
    if (MODE == 1) {
#pragma unroll
        for (int mi = 0; mi < 8; ++mi)
#pragma unroll
            for (int ni = 0; ni < 4; ++ni) {
                size_t gr = row0 + wm * 128 + mi * 16 + crow;
                size_t gc = col0 + wn * 64 + ni * 16 + ccol;
#pragma unroll
                for (int j = 0; j < 4; ++j)
                    oF[(gr + j) * 1024 + gc] = acc[mi][ni][j];
            }
    } else {
        const int region = nt >> 2;  // 0=K, 1=V, 2=R
        unsigned short* dst = (region == 0) ? oK : ((region == 1) ? oV : oR);
        const size_t cb0 = (size_t)(nt & 3) * 256;
#pragma unroll
        for (int mi = 0; mi < 8; ++mi)
#pragma unroll
            for (int ni = 0; ni < 4; ++ni) {
                size_t gr = row0 + wm * 128 + mi * 16 + crow;
                size_t gc = cb0 + wn * 64 + ni * 16 + ccol;
#pragma unroll
                for (int j = 0; j < 4; ++j) {
                    float val = acc[mi][ni][j];
                    if (region == 2) val = 1.0f / (1.0f + __expf(-val));
                    dst[(gr + j) * 1024 + gc] = f2bf(val);
                }
            }
    }
}

// ---------------- WKV segmented scan (bf16 k,v,r) ----------------
__global__ __launch_bounds__(256) void wkv_phase1(
    const unsigned short* __restrict__ kf, const unsigned short* __restrict__ vf,
    const float* __restrict__ td,
    float* __restrict__ segA, float* __restrict__ segB, float* __restrict__ segP)
{
    const int tid  = blockIdx.x * 256 + threadIdx.x;
    const int lane = tid & 63;
    const int wg   = tid >> 6;
    const int cg   = wg & 63;
    const int s    = wg >> 6;
    const int q    = cg * 64 + lane;
    const int b    = q >> 10;
    const int c    = q & (CDIM - 1);

    const float w = __expf(td[c]);

    float aa = 0.0f, bb = 0.0f, pp = -1e38f;
    size_t idx = (size_t)b * TDIM * CDIM + (size_t)(s * LSEG) * CDIM + c;
#pragma unroll 4
    for (int i = 0; i < LSEG; ++i, idx += CDIM) {
        float kt = bf2f(kf[idx]);
        float vt = bf2f(vf[idx]);
        float ww2 = pp - w;
        float p2  = fmaxf(ww2, kt);
        float e1  = __expf(ww2 - p2);
        float e2  = __expf(kt - p2);
        aa = e1 * aa + e2 * vt;
        bb = e1 * bb + e2;
        pp = p2;
    }
    segA[s * NCH + q] = aa;
    segB[s * NCH + q] = bb;
    segP[s * NCH + q] = pp;
}

__global__ __launch_bounds__(256) void wkv_phase2(
    const float* __restrict__ segA, const float* __restrict__ segB, const float* __restrict__ segP,
    const float* __restrict__ td,
    const float* __restrict__ aa0, const float* __restrict__ bb0, const float* __restrict__ pp0,
    float* __restrict__ preA, float* __restrict__ preB, float* __restrict__ preP,
    float* __restrict__ stout)
{
    const int tid = blockIdx.x * 256 + threadIdx.x;   // 0..NCH-1
    const int c = tid & (CDIM - 1);
    const float w  = __expf(td[c]);
    const float Lw = (float)LSEG * w;

    float aa = aa0[tid], bb = bb0[tid], pp = pp0[tid];
    for (int s = 0; s < SSEG; ++s) {
        preA[s * NCH + tid] = aa;
        preB[s * NCH + tid] = bb;
        preP[s * NCH + tid] = pp;
        float al = segA[s * NCH + tid];
        float bl = segB[s * NCH + tid];
        float pl = segP[s * NCH + tid];
        float ppd = pp - Lw;
        float p  = fmaxf(ppd, pl);
        float e1 = __expf(ppd - p);
        float e2 = __expf(pl - p);
        aa = e1 * aa + e2 * al;
        bb = e1 * bb + e2 * bl;
        pp = p;
    }
    stout[tid]           = aa;
    stout[NCH + tid]     = bb;
    stout[2 * NCH + tid] = pp;
}

__global__ __launch_bounds__(256) void wkv_phase3(
    const unsigned short* __restrict__ kf, const unsigned short* __restrict__ vf,
    const unsigned short* __restrict__ rb,
    const float* __restrict__ td, const float* __restrict__ tf,
    const float* __restrict__ preA, const float* __restrict__ preB, const float* __restrict__ preP,
    unsigned short* __restrict__ rwkvb)
{
    const int tid  = blockIdx.x * 256 + threadIdx.x;
    const int lane = tid & 63;
    const int wg   = tid >> 6;
    const int cg   = wg & 63;
    const int s    = wg >> 6;
    const int q    = cg * 64 + lane;
    const int b    = q >> 10;
    const int c    = q & (CDIM - 1);

    const float w = __expf(td[c]);
    const float u = tf[c];

    float aa = preA[s * NCH + q];
    float bb = preB[s * NCH + q];
    float pp = preP[s * NCH + q];

    size_t idx = (size_t)b * TDIM * CDIM + (size_t)(s * LSEG) * CDIM + c;
#pragma unroll 4
    for (int i = 0; i < LSEG; ++i, idx += CDIM) {
        float kt = bf2f(kf[idx]);
        float vt = bf2f(vf[idx]);
        float rt = bf2f(rb[idx]);
        float ww = u + kt;
        float p  = fmaxf(pp, ww);
        float e1 = __expf(pp - p);
        float e2 = __expf(ww - p);
        float wkv = (e1 * aa + e2 * vt) / (e1 * bb + e2);
        rwkvb[idx] = f2bf(rt * wkv);
        float ww2 = pp - w;
        float p2  = fmaxf(ww2, kt);
        float e1b = __expf(ww2 - p2);
        float e2b = __expf(kt - p2);
        aa = e1b * aa + e2b * vt;
        bb = e1b * bb + e2b;
        pp = p2;
    }
}

extern "C" void kernel_launch(void* const* d_in, const int* in_sizes, int n_in,
                              void* d_out, int out_size, void* d_ws, size_t ws_size,
                              hipStream_t stream) {
    const float* x   = (const float*)d_in[0];
    const float* kw  = (const float*)d_in[1];
    const float* vw  = (const float*)d_in[2];
    const float* rw  = (const float*)d_in[3];
    const float* ow  = (const float*)d_in[4];
    const float* td  = (const float*)d_in[5];
    const float* tf  = (const float*)d_in[6];
    const float* aa0 = (const float*)d_in[7];
    const float* bb0 = (const float*)d_in[8];
    const float* pp0 = (const float*)d_in[9];
    float* out = (float*)d_out;

    char* ws = (char*)d_ws;
    unsigned short* wf    = (unsigned short*)(ws);               //  6,291,456 B  [3072][1024] bf16
    unsigned short* owb   = (unsigned short*)(ws + 6291456);     //  2,097,152 B
    unsigned short* xb    = (unsigned short*)(ws + 8388608);     // 33,554,432 B
    unsigned short* kfb   = (unsigned short*)(ws + 41943040);    // 33,554,432 B
    unsigned short* vfb   = (unsigned short*)(ws + 75497472);    // 33,554,432 B
    unsigned short* rbb   = (unsigned short*)(ws + 109051904);   // 33,554,432 B
    unsigned short* rwkvb = (unsigned short*)(ws + 142606336);   // 33,554,432 B
    float* segA = (float*)(ws + 176160768);
    float* segB = (float*)(ws + 177209344);
    float* segP = (float*)(ws + 178257920);
    float* preA = (float*)(ws + 179306496);
    float* preB = (float*)(ws + 180355072);
    float* preP = (float*)(ws + 181403648);

    hipFuncSetAttribute((const void*)(gemm256<0, 12>), hipFuncAttributeMaxDynamicSharedMemorySize, 131072);
    hipFuncSetAttribute((const void*)(gemm256<1, 4>),  hipFuncAttributeMaxDynamicSharedMemorySize, 131072);

    // casts to bf16
    castk<<<2048, 256, 0, stream>>>(x, xb, MDIM * CDIM / 4);
    castw<<<4096, 256, 0, stream>>>(kw, vw, rw, ow, wf, owb);

    // fused QKV projection: [16384,1024] x [3072,1024]^T, 768 blocks
    gemm256<0, 12><<<768, 512, 131072, stream>>>(xb, wf, kfb, vfb, rbb, nullptr);

    // segmented WKV scan
    wkv_phase1<<<NCH * SSEG / 256, 256, 0, stream>>>(kfb, vfb, td, segA, segB, segP);
    wkv_phase2<<<NCH / 256, 256, 0, stream>>>(segA, segB, segP, td, aa0, bb0, pp0,
                                              preA, preB, preP, out + (size_t)MDIM * CDIM);
    wkv_phase3<<<NCH * SSEG / 256, 256, 0, stream>>>(kfb, vfb, rbb, td, tf,
                                                     preA, preB, preP, rwkvb);

    // output projection: [16384,1024] x [1024,1024]^T -> fp32 d_out, 256 blocks
    gemm256<1, 4><<<256, 512, 131072, stream>>>(rwkvb, owb, nullptr, nullptr, nullptr, out);
}

// Round 6
// 223.027 us; speedup vs baseline: 3.3545x; 1.0157x over previous
//
#include <hip/hip_runtime.h>
#include <stdint.h>

#define BDIM 4
#define TDIM 4096
#define CDIM 1024
#define MDIM (BDIM * TDIM) // 16384
#define SSEG 64            // segments along T
#define LSEG 64            // steps per segment
#define NCH  (BDIM * CDIM) // 4096 channels

#define GK   1024          // GEMM K
#define GK2  2048          // K row stride in bytes (bf16)
#define NTK  16            // K-tiles of 64

typedef __attribute__((ext_vector_type(8))) short bf16x8;
typedef __attribute__((ext_vector_type(4))) float f32x4;

__device__ __forceinline__ unsigned short f2bf(float f) {
    unsigned u = __builtin_bit_cast(unsigned, f);
    u = u + 0x7fffu + ((u >> 16) & 1u); // RNE
    return (unsigned short)(u >> 16);
}
__device__ __forceinline__ float bf2f(unsigned short h) {
    unsigned u = ((unsigned)h) << 16;
    return __builtin_bit_cast(float, u);
}

typedef __attribute__((address_space(1))) const unsigned int g_u32;
typedef __attribute__((address_space(3))) unsigned int l_u32;
__device__ __forceinline__ void gload_lds16(const void* g, void* l) {
    __builtin_amdgcn_global_load_lds((g_u32*)g, (l_u32*)l, 16, 0, 0);
}

// ---------------- fp32 -> bf16 cast (vectorized) ----------------
__global__ void castk(const float* __restrict__ src, unsigned short* __restrict__ dst, int n4) {
    int i = blockIdx.x * blockDim.x + threadIdx.x;
    int stride = gridDim.x * blockDim.x;
    for (int j = i; j < n4; j += stride) {
        float4 f = ((const float4*)src)[j];
        ushort4 o;
        o.x = f2bf(f.x); o.y = f2bf(f.y); o.z = f2bf(f.z); o.w = f2bf(f.w);
        ((ushort4*)dst)[j] = o;
    }
}

// all 4 weight matrices in one launch
__global__ void castw(const float* __restrict__ kw, const float* __restrict__ vw,
                      const float* __restrict__ rw, const float* __restrict__ ow,
                      unsigned short* __restrict__ wf, unsigned short* __restrict__ owb) {
    int i = blockIdx.x * 256 + threadIdx.x;
    int m = i >> 18, j = i & 262143;
    const float* s = (m == 0) ? kw : (m == 1) ? vw : (m == 2) ? rw : ow;
    unsigned short* d = (m < 3) ? (wf + (size_t)m * 1048576) : owb;
    float4 f = ((const float4*)s)[j];
    ushort4 o;
    o.x = f2bf(f.x); o.y = f2bf(f.y); o.z = f2bf(f.z); o.w = f2bf(f.w);
    ((ushort4*)d)[j] = o;
}

// ---------------- 256x256 8-phase bf16 GEMM (Y = A * Bw^T) ----------------
// 512 threads = 8 waves (2M x 4N). BK=64, 2 LDS slots, 1 half-tile staged per
// phase, counted vmcnt, XOR swizzle both-sides. Intrinsic s_barrier (NO
// memory clobber -- m201-exact) so the scheduler can hoist address math;
// per-thread-constant swizzle offsets precomputed (kb0/kb1, stage r/cb).
// L2-locality XCD swizzle: each XCD owns a disjoint 8-panel slice of A.
// MODE 0: fused QKV epilogue -> oK/oV(bf16), oR(sigmoid,bf16). MODE 1: fp32.
template <int MODE, int NT>
__global__ __launch_bounds__(512, 2) void gemm256(
    const unsigned short* __restrict__ A,
    const unsigned short* __restrict__ Bw,
    unsigned short* __restrict__ oK, unsigned short* __restrict__ oV,
    unsigned short* __restrict__ oR, float* __restrict__ oF)
{
    extern __shared__ char sh[];
    char* shA = sh;             // 2 slots x 2 halves x 16384 B
    char* shB = sh + 65536;

    const int tid  = threadIdx.x;
    const int wave = tid >> 6;
    const int lane = tid & 63;
    const int wm   = wave >> 2;      // 0..1 (M half)
    const int wn   = wave & 3;       // 0..3 (N quarter)
    const int lrow = lane & 15;
    const int koct = lane >> 4;      // 0..3

    // per-thread-constant swizzled k-offsets for LDS reads
    const int kb0 = (koct * 16) ^ ((lrow & 7) << 4);
    const int kb1 = kb0 ^ 64;

    // per-thread-constant stage offsets (2 chunks of 16B per stage call)
    const int sr0  = tid >> 3;                 // row of chunk 0 (0..63)
    const int sc0  = ((tid & 7) * 16) ^ ((sr0 & 7) << 4);
    const int sr1  = (512 + tid) >> 3;         // row of chunk 1 (64..127)
    const int sc1  = ((tid & 7) * 16) ^ ((sr1 & 7) << 4);
    const int sd0  = tid * 16;
    const int sd1  = 8192 + tid * 16;

    // L2-locality XCD swizzle (grid = 8 * 8 * NT blocks)
    const int bid = blockIdx.x;
    const int xcd = bid & 7;
    const int idx = bid >> 3;
    const int mt  = xcd * 8 + idx / NT;  // disjoint A-slice per XCD
    const int nt  = idx % NT;            // nt-fast: A panel L2-reused
    const size_t row0 = (size_t)mt * 256;
    const size_t col0 = (size_t)nt * 256;

    const char* gA = (const char*)A  + row0 * GK2;
    const char* gB = (const char*)Bw + col0 * GK2;

    // stage one half-tile of tile tt; part: 0=A half0, 1=A half1, 2=B half0, 3=B half1
    auto stage = [&](int tt, int part) {
        if (tt >= NTK) return;
        int slot = tt & 1;
        int isA  = (part < 2) ? 1 : 0;
        int half = part & 1;
        const char* gbase = (isA ? gA : gB) + (size_t)half * 128 * GK2 + tt * 128;
        char* lbase = (isA ? shA : shB) + (slot * 2 + half) * 16384;
        gload_lds16(gbase + (size_t)sr0 * GK2 + sc0, lbase + sd0);
        gload_lds16(gbase + (size_t)sr1 * GK2 + sc1, lbase + sd1);
    };

    // prologue: tile0 (A0,A1,B0,B1) + tile1 (A0,A1) = 6 halves
    stage(0, 0); stage(0, 1); stage(0, 2); stage(0, 3);
    stage(1, 0); stage(1, 1);
    asm volatile("s_waitcnt vmcnt(4)" ::: "memory");   // tile0 fully resident
    __builtin_amdgcn_s_barrier();

    f32x4 acc[8][4] = {};
    bf16x8 af[8][2], bf_[4][2];

    // pre-read af[0..3] of tile 0 (slot 0)
    {
        const char* ab = shA + wm * 16384 + lrow * 128;
#pragma unroll
        for (int mi = 0; mi < 4; ++mi) {
            af[mi][0] = *(const bf16x8*)(ab + mi * 2048 + kb0);
            af[mi][1] = *(const bf16x8*)(ab + mi * 2048 + kb1);
        }
    }

    for (int t = 0; t < NTK; ++t) {
        const int slot  = t & 1;
        const char* ab  = shA + (slot * 2 + wm) * 16384 + lrow * 128;
        const char* bb  = shB + (slot * 2 + (wn >> 1)) * 16384 + ((wn & 1) * 64 + lrow) * 128;
        const char* abN = shA + (((t + 1) & 1) * 2 + wm) * 16384 + lrow * 128;

        // ---- q0: read bfr[0..3]; stage B0_{t+1}; MFMA (mh0,nh0)
#pragma unroll
        for (int ni = 0; ni < 4; ++ni) {
            bf_[ni][0] = *(const bf16x8*)(bb + ni * 2048 + kb0);
            bf_[ni][1] = *(const bf16x8*)(bb + ni * 2048 + kb1);
        }
        stage(t + 1, 2);
        __builtin_amdgcn_s_barrier();
        __builtin_amdgcn_s_setprio(1);
#pragma unroll
        for (int a = 0; a < 4; ++a)
#pragma unroll
            for (int b = 0; b < 2; ++b)
#pragma unroll
                for (int ks = 0; ks < 2; ++ks)
                    acc[a][b] = __builtin_amdgcn_mfma_f32_16x16x32_bf16(af[a][ks], bf_[b][ks], acc[a][b], 0, 0, 0);
        __builtin_amdgcn_s_setprio(0);
        __builtin_amdgcn_s_barrier();

        // ---- q1: read afr[4..7]; stage B1_{t+1}; MFMA (mh0,nh1)
#pragma unroll
        for (int mi = 4; mi < 8; ++mi) {
            af[mi][0] = *(const bf16x8*)(ab + mi * 2048 + kb0);
            af[mi][1] = *(const bf16x8*)(ab + mi * 2048 + kb1);
        }
        stage(t + 1, 3);
        __builtin_amdgcn_s_barrier();
        __builtin_amdgcn_s_setprio(1);
#pragma unroll
        for (int a = 0; a < 4; ++a)
#pragma unroll
            for (int b = 0; b < 2; ++b)
#pragma unroll
                for (int ks = 0; ks < 2; ++ks)
                    acc[a][2 + b] = __builtin_amdgcn_mfma_f32_16x16x32_bf16(af[a][ks], bf_[2 + b][ks], acc[a][2 + b], 0, 0, 0);
        __builtin_amdgcn_s_setprio(0);
        __builtin_amdgcn_s_barrier();

        // ---- q2: stage A0_{t+2}; MFMA (mh1,nh0); vmcnt guards q3's prefetch
        stage(t + 2, 0);
        __builtin_amdgcn_s_barrier();
        __builtin_amdgcn_s_setprio(1);
#pragma unroll
        for (int a = 0; a < 4; ++a)
#pragma unroll
            for (int b = 0; b < 2; ++b)
#pragma unroll
                for (int ks = 0; ks < 2; ++ks)
                    acc[4 + a][b] = __builtin_amdgcn_mfma_f32_16x16x32_bf16(af[4 + a][ks], bf_[b][ks], acc[4 + a][b], 0, 0, 0);
        __builtin_amdgcn_s_setprio(0);
        if (t <= 13)      asm volatile("s_waitcnt vmcnt(6)" ::: "memory"); // A1_{t+1} resident
        else if (t == 14) asm volatile("s_waitcnt vmcnt(4)" ::: "memory");
        __builtin_amdgcn_s_barrier();

        // ---- q3: stage A1_{t+2}; prefetch afr[0..3] of t+1; MFMA (mh1,nh1)
        stage(t + 2, 1);
        if (t + 1 < NTK) {
#pragma unroll
            for (int mi = 0; mi < 4; ++mi) {
                af[mi][0] = *(const bf16x8*)(abN + mi * 2048 + kb0);
                af[mi][1] = *(const bf16x8*)(abN + mi * 2048 + kb1);
            }
        }
        __builtin_amdgcn_s_barrier();
        __builtin_amdgcn_s_setprio(1);
#pragma unroll
        for (int a = 0; a < 4; ++a)
#pragma unroll
            for (int b = 0; b < 2; ++b)
#pragma unroll
                for (int ks = 0; ks < 2; ++ks)
                    acc[4 + a][2 + b] = __builtin_amdgcn_mfma_f32_16x16x32_bf16(af[4 + a][ks], bf_[2 + b][ks], acc[4 + a][2 + b], 0, 0, 0);
        __builtin_amdgcn_s_setprio(0);
        if (t <= 13)      asm volatile("s_waitcnt vmcnt(4)" ::: "memory"); // B_{t+1} resident
        else if (t == 14) asm volatile("s_waitcnt vmcnt(0)" ::: "memory");
        __builtin_amdgcn_s_barrier();
    }

    // ---- epilogue: C/D frag layout col=lane&15, row=(lane>>4)*4+j
    const int crow = (lane >> 4) * 4;
    const int ccol = lane & 15;
    if (MODE == 1) {
#pragma unroll
        for (int mi = 0; mi < 8; ++mi)
#pragma unroll
            for (int ni = 0; ni < 4; ++ni) {
                size_t gr = row0 + wm * 128 + mi * 16 + crow;
                size_t gc = col0 + wn * 64 + ni * 16 + ccol;
#pragma unroll
                for (int j = 0; j < 4; ++j)
                    oF[(gr + j) * 1024 + gc] = acc[mi][ni][j];
            }
    } else {
        const int region = nt >> 2;  // 0=K, 1=V, 2=R
        unsigned short* dst = (region == 0) ? oK : ((region == 1) ? oV : oR);
        const size_t cb0 = (size_t)(nt & 3) * 256;
#pragma unroll
        for (int mi = 0; mi < 8; ++mi)
#pragma unroll
            for (int ni = 0; ni < 4; ++ni) {
                size_t gr = row0 + wm * 128 + mi * 16 + crow;
                size_t gc = cb0 + wn * 64 + ni * 16 + ccol;
#pragma unroll
                for (int j = 0; j < 4; ++j) {
                    float val = acc[mi][ni][j];
                    if (region == 2) val = 1.0f / (1.0f + __expf(-val));
                    dst[(gr + j) * 1024 + gc] = f2bf(val);
                }
            }
    }
}

// ---------------- WKV segmented scan (bf16 k,v,r) ----------------
__global__ __launch_bounds__(256) void wkv_phase1(
    const unsigned short* __restrict__ kf, const unsigned short* __restrict__ vf,
    const float* __restrict__ td,
    float* __restrict__ segA, float* __restrict__ segB, float* __restrict__ segP)
{
    const int tid  = blockIdx.x * 256 + threadIdx.x;
    const int lane = tid & 63;
    const int wg   = tid >> 6;
    const int cg   = wg & 63;
    const int s    = wg >> 6;
    const int q    = cg * 64 + lane;
    const int b    = q >> 10;
    const int c    = q & (CDIM - 1);

    const float w = __expf(td[c]);

    float aa = 0.0f, bb = 0.0f, pp = -1e38f;
    size_t idx = (size_t)b * TDIM * CDIM + (size_t)(s * LSEG) * CDIM + c;
#pragma unroll 4
    for (int i = 0; i < LSEG; ++i, idx += CDIM) {
        float kt = bf2f(kf[idx]);
        float vt = bf2f(vf[idx]);
        float ww2 = pp - w;
        float p2  = fmaxf(ww2, kt);
        float e1  = __expf(ww2 - p2);
        float e2  = __expf(kt - p2);
        aa = e1 * aa + e2 * vt;
        bb = e1 * bb + e2;
        pp = p2;
    }
    segA[s * NCH + q] = aa;
    segB[s * NCH + q] = bb;
    segP[s * NCH + q] = pp;
}

__global__ __launch_bounds__(256) void wkv_phase2(
    const float* __restrict__ segA, const float* __restrict__ segB, const float* __restrict__ segP,
    const float* __restrict__ td,
    const float* __restrict__ aa0, const float* __restrict__ bb0, const float* __restrict__ pp0,
    float* __restrict__ preA, float* __restrict__ preB, float* __restrict__ preP,
    float* __restrict__ stout)
{
    const int tid = blockIdx.x * 256 + threadIdx.x;   // 0..NCH-1
    const int c = tid & (CDIM - 1);
    const float w  = __expf(td[c]);
    const float Lw = (float)LSEG * w;

    float aa = aa0[tid], bb = bb0[tid], pp = pp0[tid];
    for (int s = 0; s < SSEG; ++s) {
        preA[s * NCH + tid] = aa;
        preB[s * NCH + tid] = bb;
        preP[s * NCH + tid] = pp;
        float al = segA[s * NCH + tid];
        float bl = segB[s * NCH + tid];
        float pl = segP[s * NCH + tid];
        float ppd = pp - Lw;
        float p  = fmaxf(ppd, pl);
        float e1 = __expf(ppd - p);
        float e2 = __expf(pl - p);
        aa = e1 * aa + e2 * al;
        bb = e1 * bb + e2 * bl;
        pp = p;
    }
    stout[tid]           = aa;
    stout[NCH + tid]     = bb;
    stout[2 * NCH + tid] = pp;
}

__global__ __launch_bounds__(256) void wkv_phase3(
    const unsigned short* __restrict__ kf, const unsigned short* __restrict__ vf,
    const unsigned short* __restrict__ rb,
    const float* __restrict__ td, const float* __restrict__ tf,
    const float* __restrict__ preA, const float* __restrict__ preB, const float* __restrict__ preP,
    unsigned short* __restrict__ rwkvb)
{
    const int tid  = blockIdx.x * 256 + threadIdx.x;
    const int lane = tid & 63;
    const int wg   = tid >> 6;
    const int cg   = wg & 63;
    const int s    = wg >> 6;
    const int q    = cg * 64 + lane;
    const int b    = q >> 10;
    const int c    = q & (CDIM - 1);

    const float w = __expf(td[c]);
    const float u = tf[c];

    float aa = preA[s * NCH + q];
    float bb = preB[s * NCH + q];
    float pp = preP[s * NCH + q];

    size_t idx = (size_t)b * TDIM * CDIM + (size_t)(s * LSEG) * CDIM + c;
#pragma unroll 4
    for (int i = 0; i < LSEG; ++i, idx += CDIM) {
        float kt = bf2f(kf[idx]);
        float vt = bf2f(vf[idx]);
        float rt = bf2f(rb[idx]);
        float ww = u + kt;
        float p  = fmaxf(pp, ww);
        float e1 = __expf(pp - p);
        float e2 = __expf(ww - p);
        float wkv = (e1 * aa + e2 * vt) / (e1 * bb + e2);
        rwkvb[idx] = f2bf(rt * wkv);
        float ww2 = pp - w;
        float p2  = fmaxf(ww2, kt);
        float e1b = __expf(ww2 - p2);
        float e2b = __expf(kt - p2);
        aa = e1b * aa + e2b * vt;
        bb = e1b * bb + e2b;
        pp = p2;
    }
}

extern "C" void kernel_launch(void* const* d_in, const int* in_sizes, int n_in,
                              void* d_out, int out_size, void* d_ws, size_t ws_size,
                              hipStream_t stream) {
    const float* x   = (const float*)d_in[0];
    const float* kw  = (const float*)d_in[1];
    const float* vw  = (const float*)d_in[2];
    const float* rw  = (const float*)d_in[3];
    const float* ow  = (const float*)d_in[4];
    const float* td  = (const float*)d_in[5];
    const float* tf  = (const float*)d_in[6];
    const float* aa0 = (const float*)d_in[7];
    const float* bb0 = (const float*)d_in[8];
    const float* pp0 = (const float*)d_in[9];
    float* out = (float*)d_out;

    char* ws = (char*)d_ws;
    unsigned short* wf    = (unsigned short*)(ws);               //  6,291,456 B  [3072][1024] bf16
    unsigned short* owb   = (unsigned short*)(ws + 6291456);     //  2,097,152 B
    unsigned short* xb    = (unsigned short*)(ws + 8388608);     // 33,554,432 B
    unsigned short* kfb   = (unsigned short*)(ws + 41943040);    // 33,554,432 B
    unsigned short* vfb   = (unsigned short*)(ws + 75497472);    // 33,554,432 B
    unsigned short* rbb   = (unsigned short*)(ws + 109051904);   // 33,554,432 B
    unsigned short* rwkvb = (unsigned short*)(ws + 142606336);   // 33,554,432 B
    float* segA = (float*)(ws + 176160768);
    float* segB = (float*)(ws + 177209344);
    float* segP = (float*)(ws + 178257920);
    float* preA = (float*)(ws + 179306496);
    float* preB = (float*)(ws + 180355072);
    float* preP = (float*)(ws + 181403648);

    hipFuncSetAttribute((const void*)(gemm256<0, 12>), hipFuncAttributeMaxDynamicSharedMemorySize, 131072);
    hipFuncSetAttribute((const void*)(gemm256<1, 4>),  hipFuncAttributeMaxDynamicSharedMemorySize, 131072);

    // casts to bf16
    castk<<<2048, 256, 0, stream>>>(x, xb, MDIM * CDIM / 4);
    castw<<<4096, 256, 0, stream>>>(kw, vw, rw, ow, wf, owb);

    // fused QKV projection: [16384,1024] x [3072,1024]^T, 768 blocks
    gemm256<0, 12><<<768, 512, 131072, stream>>>(xb, wf, kfb, vfb, rbb, nullptr);

    // segmented WKV scan
    wkv_phase1<<<NCH * SSEG / 256, 256, 0, stream>>>(kfb, vfb, td, segA, segB, segP);
    wkv_phase2<<<NCH / 256, 256, 0, stream>>>(segA, segB, segP, td, aa0, bb0, pp0,
                                              preA, preB, preP, out + (size_t)MDIM * CDIM);
    wkv_phase3<<<NCH * SSEG / 256, 256, 0, stream>>>(kfb, vfb, rbb, td, tf,
                                                     preA, preB, preP, rwkvb);

    // output projection: [16384,1024] x [1024,1024]^T -> fp32 d_out, 256 blocks
    gemm256<1, 4><<<256, 512, 131072, stream>>>(rwkvb, owb, nullptr, nullptr, nullptr, out);
}